// Round 8
// baseline (247.222 us; speedup 1.0000x reference)
//
#include <hip/hip_runtime.h>
#include <hip/hip_bf16.h>
#include <stdint.h>

#define S_LEN  2048
#define DMODEL 2048
#define NHEADS 16
#define DHEAD  128
#define NBATCH 2
#define MROWS  (NBATCH * S_LEN)   // 4096

typedef __bf16 bf16_t;
typedef __bf16 bf16x8 __attribute__((ext_vector_type(8)));
typedef float  f32x4  __attribute__((ext_vector_type(4)));
typedef float  f32x16 __attribute__((ext_vector_type(16)));

#define MFMA_BF16(A, B, C) __builtin_amdgcn_mfma_f32_16x16x32_bf16((A), (B), (C), 0, 0, 0)
#define MFMA32(A, B, C)    __builtin_amdgcn_mfma_f32_32x32x16_bf16((A), (B), (C), 0, 0, 0)

__device__ __forceinline__ void gload_lds16(const void* g, void* l) {
  __builtin_amdgcn_global_load_lds(
      (__attribute__((address_space(1))) uint32_t*)(uintptr_t)g,
      (__attribute__((address_space(3))) uint32_t*)l,
      16, 0, 0);
}

__device__ __forceinline__ unsigned pk2(float lo, float hi) {
  const unsigned short a = __builtin_bit_cast(unsigned short, (bf16_t)lo);
  const unsigned short b = __builtin_bit_cast(unsigned short, (bf16_t)hi);
  return (unsigned)a | ((unsigned)b << 16);
}

// ---------------------------------------------------------------- cast x -> bf16
__global__ __launch_bounds__(256) void cast_kernel(const float* __restrict__ X,
                                                   bf16_t* __restrict__ Xb) {
  const int i = blockIdx.x * 256 + threadIdx.x;
  const f32x4 a = ((const f32x4*)X)[2 * i];
  const f32x4 b = ((const f32x4*)X)[2 * i + 1];
  bf16x8 o;
#pragma unroll
  for (int j = 0; j < 4; ++j) { o[j] = (bf16_t)a[j]; o[j + 4] = (bf16_t)b[j]; }
  ((bf16x8*)Xb)[i] = o;
}

// ---------------------------------------------------- W [K][N] f32 -> Wt [N][K] bf16
__global__ __launch_bounds__(256) void transpose_cast(
    const float* __restrict__ W0, const float* __restrict__ W1,
    const float* __restrict__ W2, const float* __restrict__ W3,
    bf16_t* __restrict__ T0, bf16_t* __restrict__ T1,
    bf16_t* __restrict__ T2, bf16_t* __restrict__ T3) {
  const float* W; bf16_t* T;
  switch (blockIdx.z) {
    case 0:  W = W0; T = T0; break;
    case 1:  W = W1; T = T1; break;
    case 2:  W = W2; T = T2; break;
    default: W = W3; T = T3; break;
  }
  __shared__ float tile[64][65];
  const int r0 = blockIdx.y * 64;
  const int c0 = blockIdx.x * 64;
  const int tx = threadIdx.x & 63;
  const int ty = threadIdx.x >> 6;
#pragma unroll
  for (int i = 0; i < 16; ++i) {
    const int r = ty + i * 4;
    tile[r][tx] = W[(size_t)(r0 + r) * DMODEL + c0 + tx];
  }
  __syncthreads();
#pragma unroll
  for (int i = 0; i < 16; ++i) {
    const int r = ty + i * 4;
    T[(size_t)(c0 + r) * DMODEL + r0 + tx] = (bf16_t)tile[tx][r];
  }
}

// -------------------------------------- V [bh][2048][128] -> VT [bh][128][2048] bf16
__global__ __launch_bounds__(256) void transpose_v(const bf16_t* __restrict__ V,
                                                   bf16_t* __restrict__ VT) {
  __shared__ bf16_t tile[64 * 64];   // XOR-swizzled 64x64 tile
  const int bh = blockIdx.z;
  const int s0 = blockIdx.x * 64;
  const int d0 = blockIdx.y * 64;
  const bf16_t* src = V + ((size_t)bh * S_LEN + s0) * DHEAD + d0;
#pragma unroll
  for (int i = 0; i < 2; ++i) {
    const int v = threadIdx.x + i * 256;     // 0..511
    const int r = v >> 3, ch = v & 7;
    *(bf16x8*)&tile[r * 64 + ((ch ^ ((r >> 3) & 7)) << 3)] =
        *(const bf16x8*)(src + (size_t)r * DHEAD + ch * 8);
  }
  __syncthreads();
  bf16_t* dst = VT + ((size_t)bh * DHEAD + d0) * S_LEN + s0;
#pragma unroll
  for (int i = 0; i < 2; ++i) {
    const int v = threadIdx.x + i * 256;
    const int d = v >> 3, j = v & 7;         // out row d, col block j
    bf16x8 o;
#pragma unroll
    for (int e = 0; e < 8; ++e) {
      const int row = j * 8 + e;
      o[e] = tile[row * 64 + (((d >> 3) ^ j) << 3) + (d & 7)];
    }
    *(bf16x8*)(dst + (size_t)d * S_LEN + j * 8) = o;
  }
}

// ------------------------------------------- GEMM body: BM=128 BN=256 BK=64
// R4 schedule (proven: 0 conflicts) with 32x32x16 MFMA (half the instructions,
// 2/3 the LDS frag reads). 8 waves 2m x 4n, per-wave 64x64 = f32x16 acc[2][2].
// Operand layout (HW-verified in attn): row = l31, k-elems at [s*16 + hi*8, +8)
// -> LDS slot (2s+hi) ^ (row&7). C/D: col = l31, row = (r&3)+8*(r>>2)+4*hi.
template <int MODE>
__device__ __forceinline__ void gemm8_body(const bf16_t* __restrict__ A,
                                           const bf16_t* __restrict__ Bt,
                                           const float* __restrict__ bias,
                                           void* __restrict__ out) {
  __shared__ __align__(16) char lds8[2 * 49152];   // 96 KB
  const int tid  = threadIdx.x;
  const int lane = tid & 63;
  const int w    = tid >> 6;
  const int l31  = lane & 31;
  const int hi   = lane >> 5;
  const int wm   = w >> 2;       // 0..1
  const int wn   = w & 3;        // 0..3
  const int m0   = blockIdx.y * 128;
  const int n0   = blockIdx.x * 256;

  f32x16 acc[2][2];
#pragma unroll
  for (int i = 0; i < 2; ++i)
#pragma unroll
    for (int j = 0; j < 2; ++j)
#pragma unroll
      for (int e = 0; e < 16; ++e) acc[i][j][e] = 0.f;

  const int st_r0 = tid >> 3;
  const int st_ch = tid & 7;

  auto stage = [&](int tile, int r) {
    if (tile >= DMODEL / 64) return;
    const int kt = tile << 6;
    char* db = lds8 + (tile & 1) * 49152 + r * 16384 + w * 1024;
    const bf16_t* sb = (r == 0) ? (A + (size_t)m0 * DMODEL + kt)
                                : (Bt + (size_t)(n0 + ((r - 1) << 7)) * DMODEL + kt);
#pragma unroll
    for (int jj = 0; jj < 2; ++jj) {
      const int row = jj * 64 + st_r0;
      gload_lds16(sb + (size_t)row * DMODEL + ((st_ch ^ (row & 7)) << 3),
                  db + jj * 8192);
    }
  };

  stage(0, 0); stage(0, 1); stage(0, 2); stage(1, 0);
  asm volatile("s_waitcnt vmcnt(2)" ::: "memory");
  __builtin_amdgcn_s_barrier();

#pragma unroll 2
  for (int t = 0; t < DMODEL / 64; ++t) {
    const char* cb  = lds8 + (t & 1) * 49152;
    const char* cbB = cb + 16384 + (wn >> 1) * 16384;
    bf16x8 af[2][4], bf0[4], bf1[4];

    // ---- p0: A frags (8 reads) + B nj=0 frags (4); stage(t+1,B0),(t+1,B1)
#pragma unroll
    for (int mi = 0; mi < 2; ++mi) {
      const int row = wm * 64 + mi * 32 + l31;
      const char* rp = cb + row * 128;
      const int swz = (row & 7) << 4;
#pragma unroll
      for (int s = 0; s < 4; ++s)
        af[mi][s] = *(const bf16x8*)(rp + ((((s << 1) | hi) << 4) ^ swz));
    }
    {
      const int row = (wn & 1) * 64 + l31;
      const char* rp = cbB + row * 128;
      const int swz = (row & 7) << 4;
#pragma unroll
      for (int s = 0; s < 4; ++s)
        bf0[s] = *(const bf16x8*)(rp + ((((s << 1) | hi) << 4) ^ swz));
    }
    stage(t + 1, 1); stage(t + 1, 2);
    __builtin_amdgcn_s_barrier();
    asm volatile("s_waitcnt lgkmcnt(0)" ::: "memory");
    __builtin_amdgcn_s_setprio(1);
#pragma unroll
    for (int mi = 0; mi < 2; ++mi)
#pragma unroll
      for (int s = 0; s < 4; ++s)
        acc[mi][0] = MFMA32(af[mi][s], bf0[s], acc[mi][0]);
    __builtin_amdgcn_s_setprio(0);
    __builtin_amdgcn_s_barrier();

    // ---- p1: B nj=1 frags (4); stage(t+2,A)
    {
      const int row = (wn & 1) * 64 + 32 + l31;
      const char* rp = cbB + row * 128;
      const int swz = (row & 7) << 4;
#pragma unroll
      for (int s = 0; s < 4; ++s)
        bf1[s] = *(const bf16x8*)(rp + ((((s << 1) | hi) << 4) ^ swz));
    }
    stage(t + 2, 0);
    __builtin_amdgcn_s_barrier();
    asm volatile("s_waitcnt lgkmcnt(0)" ::: "memory");
    __builtin_amdgcn_s_setprio(1);
#pragma unroll
    for (int mi = 0; mi < 2; ++mi)
#pragma unroll
      for (int s = 0; s < 4; ++s)
        acc[mi][1] = MFMA32(af[mi][s], bf1[s], acc[mi][1]);
    __builtin_amdgcn_s_setprio(0);
    if (t < DMODEL / 64 - 2) asm volatile("s_waitcnt vmcnt(2)" ::: "memory");
    else                     asm volatile("s_waitcnt vmcnt(0)" ::: "memory");
    __builtin_amdgcn_s_barrier();
  }

#pragma unroll
  for (int mi = 0; mi < 2; ++mi) {
#pragma unroll
    for (int nj = 0; nj < 2; ++nj) {
      const int n    = n0 + wn * 64 + nj * 32 + l31;
      const float bb = bias[n];
#pragma unroll
      for (int r = 0; r < 16; ++r) {
        const int m   = m0 + wm * 64 + mi * 32 + (r & 3) + 8 * (r >> 2) + 4 * hi;
        const float v = acc[mi][nj][r] + bb;
        if (MODE == 0) {
          const int b = m >> 11, s = m & (S_LEN - 1);
          const int h = n >> 7,  d = n & (DHEAD - 1);
          ((bf16_t*)out)[((size_t)(b * NHEADS + h) * S_LEN + s) * DHEAD + d] = (bf16_t)v;
        } else {
          ((float*)out)[(size_t)m * DMODEL + n] = v;
        }
      }
    }
  }
}

__global__ __launch_bounds__(512, 2) void gemm_qkv(
    const bf16_t* __restrict__ Xb,
    const bf16_t* __restrict__ WqT, const bf16_t* __restrict__ WkT,
    const bf16_t* __restrict__ WvT,
    const float* __restrict__ bq, const float* __restrict__ bk,
    const float* __restrict__ bv,
    bf16_t* __restrict__ Qg, bf16_t* __restrict__ Kg, bf16_t* __restrict__ Vg) {
  const bf16_t* Bt; const float* bias; bf16_t* out;
  if (blockIdx.z == 0)      { Bt = WqT; bias = bq; out = Qg; }
  else if (blockIdx.z == 1) { Bt = WkT; bias = bk; out = Kg; }
  else                      { Bt = WvT; bias = bv; out = Vg; }
  gemm8_body<0>(Xb, Bt, bias, out);
}

__global__ __launch_bounds__(512, 2) void gemm_out(
    const bf16_t* __restrict__ Ctx, const bf16_t* __restrict__ WoT,
    const float* __restrict__ bo, float* __restrict__ out) {
  gemm8_body<1>(Ctx, WoT, bo, out);
}

// --------------------------------------------------------------- flash attention
// 4 waves x 32 q-rows = 128 q/block, KVBLK=64, swapped QK^T, in-register softmax.
// K/V staged DIRECTLY via global_load_lds (linear dest, inverse-swizzled source,
// chunk ^= row&7) into unpadded tiles: K[64][128] (256B rows), VT[128][64]
// (128B rows). One barrier + one vmcnt(0) per tile.
#define KTILE_B 16384
#define VTILE_B 16384
#define ABUF_B  (KTILE_B + VTILE_B)   // 32 KB per buffer

__global__ __launch_bounds__(256, 2) void attn_kernel(
    const bf16_t* __restrict__ Qg, const bf16_t* __restrict__ Kg,
    const bf16_t* __restrict__ VTg, bf16_t* __restrict__ ctx) {
  __shared__ __align__(16) char ldsbuf[2][ABUF_B];
  __shared__ float lbuf[4][32];

  const int tid  = threadIdx.x;
  const int lane = tid & 63;
  const int w    = tid >> 6;
  const int l31  = lane & 31;
  const int hi   = lane >> 5;

  const int id   = blockIdx.x;                  // 512 blocks
  const int bh   = id & 31;
  const int jraw = id >> 5;
  const int j    = (jraw < 8) ? jraw : 23 - jraw;   // pair (j,15-j) co-resident
  const int q0   = j * 128;
  const int qw   = q0 + w * 32;
  const int tq   = (qw + 31) >> 6;              // diagonal tile index for this wave
  const int NT   = (q0 + 128) >> 6;             // tiles this block processes

  const size_t bho = (size_t)bh * S_LEN * DHEAD;
  const bf16_t* Qb  = Qg + bho;
  const bf16_t* Kb  = Kg + bho;
  const bf16_t* VTb = VTg + bho;                // [128][2048]

  // direct-to-LDS staging of one K/V tile (8 gload_lds per thread)
  auto stageT = [&](int t) {
    const int kt = t << 6;
    char* dst = ldsbuf[t & 1];
#pragma unroll
    for (int i = 0; i < 4; ++i) {                 // K: 64 rows x 256B
      const int c   = i * 256 + tid;              // 0..1023
      const int row = c >> 4, ch = c & 15;
      gload_lds16(Kb + (size_t)(kt + row) * DHEAD + ((ch ^ (row & 7)) << 3),
                  dst + (i * 256 + (tid & ~63)) * 16);
    }
#pragma unroll
    for (int i = 0; i < 4; ++i) {                 // VT: 128 rows x 128B
      const int c   = i * 256 + tid;
      const int row = c >> 3, ch = c & 7;
      gload_lds16(VTb + (size_t)row * S_LEN + kt + ((ch ^ (row & 7)) << 3),
                  dst + KTILE_B + (i * 256 + (tid & ~63)) * 16);
    }
  };

  // Q fragments: lane holds Q[qw+l31][16s+8hi .. +8]
  bf16x8 qreg[8];
#pragma unroll
  for (int s = 0; s < 8; ++s)
    qreg[s] = *(const bf16x8*)(Qb + (size_t)(qw + l31) * DHEAD + s * 16 + hi * 8);

  f32x16 oacc[4];
#pragma unroll
  for (int d0 = 0; d0 < 4; ++d0)
#pragma unroll
    for (int e = 0; e < 16; ++e) oacc[d0][e] = 0.f;

  float m = -1e30f, lsum = 0.f;
  const float sc2 = 0.12751751135f;             // log2(e)/sqrt(128)

  // prologue: stage tile 0
  stageT(0);
  asm volatile("s_waitcnt vmcnt(0)" ::: "memory");
  __syncthreads();

  for (int t = 0; t < NT; ++t) {
    const char* bK = ldsbuf[t & 1];
    const char* bV = bK + KTILE_B;
    if (t + 1 < NT) stageT(t + 1);   // in flight during compute

    if (t <= tq) {
      const int kt = t << 6;
      // ---- swapped QK^T: D[kv][q], lane column q = l31
      f32x16 stt[2];
#pragma unroll
      for (int kh = 0; kh < 2; ++kh)
#pragma unroll
        for (int e = 0; e < 16; ++e) stt[kh][e] = 0.f;
#pragma unroll
      for (int kh = 0; kh < 2; ++kh) {
        const int row = kh * 32 + l31;
        const char* rb = bK + row * 256;
        const int swz = (row & 7) << 4;
#pragma unroll
        for (int s = 0; s < 8; ++s) {
          const bf16x8 kf = *(const bf16x8*)(rb + ((((s << 1) | hi) << 4) ^ swz));
          stt[kh] = MFMA32(kf, qreg[s], stt[kh]);
        }
      }
      // ---- causal mask (diagonal tile only)
      if (t == tq) {
        const int qg = qw + l31;
#pragma unroll
        for (int kh = 0; kh < 2; ++kh)
#pragma unroll
          for (int r = 0; r < 16; ++r) {
            const int kv = kt + kh * 32 + (r & 3) + 8 * (r >> 2) + 4 * hi;
            stt[kh][r] = (kv > qg) ? -1e30f : stt[kh][r];
          }
      }
      // ---- row max (in-lane + partner via shfl_xor 32)
      float pm = stt[0][0];
#pragma unroll
      for (int kh = 0; kh < 2; ++kh)
#pragma unroll
        for (int r = 0; r < 16; ++r)
          if (kh | r) pm = fmaxf(pm, stt[kh][r]);
      pm = fmaxf(pm, __shfl_xor(pm, 32));
      const float pmax = pm * sc2;
      // ---- defer-max rescale (T13, THR=8)
      if (!__all(pmax <= m + 8.f)) {
        const float mn   = fmaxf(m, pmax);
        const float corr = __builtin_amdgcn_exp2f(m - mn);
        m = mn;
        lsum *= corr;
        if (!hi) lbuf[w][l31] = corr;
#pragma unroll
        for (int r = 0; r < 16; ++r) {
          const float cr = lbuf[w][(r & 3) + 8 * (r >> 2) + 4 * hi];
#pragma unroll
          for (int d0 = 0; d0 < 4; ++d0) oacc[d0][r] *= cr;
        }
      }
      // ---- p = exp2(s*sc2 - m), row sum
      float rs = 0.f;
#pragma unroll
      for (int kh = 0; kh < 2; ++kh)
#pragma unroll
        for (int r = 0; r < 16; ++r) {
          const float p = __builtin_amdgcn_exp2f(__builtin_fmaf(stt[kh][r], sc2, -m));
          stt[kh][r] = p;
          rs += p;
        }
      rs += __shfl_xor(rs, 32);
      lsum += rs;
      // ---- pack P to bf16 A-fragments: manual pack + shfl_xor(32) + hi-select
      unsigned pw_[2][8];
#pragma unroll
      for (int kh = 0; kh < 2; ++kh)
#pragma unroll
        for (int jj = 0; jj < 8; ++jj)
          pw_[kh][jj] = pk2(stt[kh][2 * jj], stt[kh][2 * jj + 1]);
      bf16x8 pa[4];
#pragma unroll
      for (int kh = 0; kh < 2; ++kh)
#pragma unroll
        for (int c2 = 0; c2 < 2; ++c2) {
          const unsigned o0 = pw_[kh][4 * c2 + 0], o1 = pw_[kh][4 * c2 + 1];
          const unsigned o2 = pw_[kh][4 * c2 + 2], o3 = pw_[kh][4 * c2 + 3];
          const unsigned p0 = (unsigned)__shfl_xor((int)o0, 32);
          const unsigned p1 = (unsigned)__shfl_xor((int)o1, 32);
          const unsigned p2 = (unsigned)__shfl_xor((int)o2, 32);
          const unsigned p3 = (unsigned)__shfl_xor((int)o3, 32);
          union { unsigned u[4]; bf16x8 v; } uu;
          uu.u[0] = hi ? p2 : o0;
          uu.u[1] = hi ? p3 : o1;
          uu.u[2] = hi ? o2 : p0;
          uu.u[3] = hi ? o3 : p1;
          pa[2 * kh + c2] = uu.v;
        }
      // ---- PV: D[q][d] += P * V
#pragma unroll
      for (int d0 = 0; d0 < 4; ++d0) {
        const int row = d0 * 32 + l31;
        const char* rb = bV + row * 128;
        const int swz = (row & 7) << 4;
#pragma unroll
        for (int ks = 0; ks < 4; ++ks) {
          const bf16x8 vb = *(const bf16x8*)(rb + ((((ks << 1) | hi) << 4) ^ swz));
          oacc[d0] = MFMA32(pa[ks], vb, oacc[d0]);
        }
      }
    }
    // tile t+1 staged into other buffer; drain + release buffer t
    asm volatile("s_waitcnt vmcnt(0)" ::: "memory");
    __syncthreads();
  }

  // ---- epilogue: normalize, write ctx [B][S][H*D] bf16
  if (!hi) lbuf[w][l31] = 1.0f / lsum;
  const int b = bh >> 4, h = bh & 15;
#pragma unroll
  for (int r = 0; r < 16; ++r) {
    const int cro = (r & 3) + 8 * (r >> 2) + 4 * hi;
    const float li = lbuf[w][cro];
    const size_t base = ((size_t)(b * S_LEN + qw + cro)) * DMODEL + h * DHEAD;
#pragma unroll
    for (int d0 = 0; d0 < 4; ++d0)
      ctx[base + d0 * 32 + l31] = (bf16_t)(oacc[d0][r] * li);
  }
}

// ------------------------------------------------------------------------- launch
extern "C" void kernel_launch(void* const* d_in, const int* in_sizes, int n_in,
                              void* d_out, int out_size, void* d_ws, size_t ws_size,
                              hipStream_t stream) {
  const float* x  = (const float*)d_in[0];
  const float* Wq = (const float*)d_in[1];
  const float* bq = (const float*)d_in[2];
  const float* Wk = (const float*)d_in[3];
  const float* bk = (const float*)d_in[4];
  const float* Wv = (const float*)d_in[5];
  const float* bv = (const float*)d_in[6];
  const float* Wo = (const float*)d_in[7];
  const float* bo = (const float*)d_in[8];

  char* ws = (char*)d_ws;
  const size_t MB = 1ull << 20;
  bf16_t* Xb  = (bf16_t*)(ws + 0);          // x bf16 (dead after gemm_qkv)
  bf16_t* VTg = (bf16_t*)(ws + 0);          // V^T reuses Xb's slot
  bf16_t* WqT = (bf16_t*)(ws + 16 * MB);
  bf16_t* WkT = (bf16_t*)(ws + 24 * MB);
  bf16_t* WvT = (bf16_t*)(ws + 32 * MB);
  bf16_t* WoT = (bf16_t*)(ws + 40 * MB);
  bf16_t* Qg  = (bf16_t*)(ws + 48 * MB);
  bf16_t* Kg  = (bf16_t*)(ws + 64 * MB);
  bf16_t* Vg  = (bf16_t*)(ws + 80 * MB);
  bf16_t* Ctx = (bf16_t*)(ws + 96 * MB);
  if (ws_size < 112 * MB) return;

  cast_kernel<<<dim3(MROWS * DMODEL / (256 * 8)), 256, 0, stream>>>(x, Xb);
  transpose_cast<<<dim3(32, 32, 4), 256, 0, stream>>>(Wq, Wk, Wv, Wo, WqT, WkT, WvT, WoT);
  gemm_qkv<<<dim3(DMODEL / 256, MROWS / 128, 3), 512, 0, stream>>>(
      Xb, WqT, WkT, WvT, bq, bk, bv, Qg, Kg, Vg);
  transpose_v<<<dim3(32, 2, 32), 256, 0, stream>>>(Vg, VTg);
  attn_kernel<<<dim3(512), 256, 0, stream>>>(Qg, Kg, VTg, Ctx);
  gemm_out<<<dim3(DMODEL / 256, MROWS / 128), 512, 0, stream>>>(Ctx, WoT, bo, (float*)d_out);
}

// Round 9
// 240.122 us; speedup vs baseline: 1.0296x; 1.0296x over previous
//
#include <hip/hip_runtime.h>
#include <hip/hip_bf16.h>
#include <stdint.h>

#define S_LEN  2048
#define DMODEL 2048
#define NHEADS 16
#define DHEAD  128
#define NBATCH 2
#define MROWS  (NBATCH * S_LEN)   // 4096

typedef __bf16 bf16_t;
typedef __bf16 bf16x8 __attribute__((ext_vector_type(8)));
typedef float  f32x4  __attribute__((ext_vector_type(4)));
typedef float  f32x16 __attribute__((ext_vector_type(16)));

#define MFMA_BF16(A, B, C) __builtin_amdgcn_mfma_f32_16x16x32_bf16((A), (B), (C), 0, 0, 0)
#define MFMA32(A, B, C)    __builtin_amdgcn_mfma_f32_32x32x16_bf16((A), (B), (C), 0, 0, 0)

__device__ __forceinline__ void gload_lds16(const void* g, void* l) {
  __builtin_amdgcn_global_load_lds(
      (__attribute__((address_space(1))) uint32_t*)(uintptr_t)g,
      (__attribute__((address_space(3))) uint32_t*)l,
      16, 0, 0);
}

__device__ __forceinline__ unsigned pk2(float lo, float hi) {
  const unsigned short a = __builtin_bit_cast(unsigned short, (bf16_t)lo);
  const unsigned short b = __builtin_bit_cast(unsigned short, (bf16_t)hi);
  return (unsigned)a | ((unsigned)b << 16);
}

// ---------------------------------------------------------------- cast x -> bf16
__global__ __launch_bounds__(256) void cast_kernel(const float* __restrict__ X,
                                                   bf16_t* __restrict__ Xb) {
  const int i = blockIdx.x * 256 + threadIdx.x;
  const f32x4 a = ((const f32x4*)X)[2 * i];
  const f32x4 b = ((const f32x4*)X)[2 * i + 1];
  bf16x8 o;
#pragma unroll
  for (int j = 0; j < 4; ++j) { o[j] = (bf16_t)a[j]; o[j + 4] = (bf16_t)b[j]; }
  ((bf16x8*)Xb)[i] = o;
}

// ---------------------------------------------------- W [K][N] f32 -> Wt [N][K] bf16
__global__ __launch_bounds__(256) void transpose_cast(
    const float* __restrict__ W0, const float* __restrict__ W1,
    const float* __restrict__ W2, const float* __restrict__ W3,
    bf16_t* __restrict__ T0, bf16_t* __restrict__ T1,
    bf16_t* __restrict__ T2, bf16_t* __restrict__ T3) {
  const float* W; bf16_t* T;
  switch (blockIdx.z) {
    case 0:  W = W0; T = T0; break;
    case 1:  W = W1; T = T1; break;
    case 2:  W = W2; T = T2; break;
    default: W = W3; T = T3; break;
  }
  __shared__ float tile[64][65];
  const int r0 = blockIdx.y * 64;
  const int c0 = blockIdx.x * 64;
  const int tx = threadIdx.x & 63;
  const int ty = threadIdx.x >> 6;
#pragma unroll
  for (int i = 0; i < 16; ++i) {
    const int r = ty + i * 4;
    tile[r][tx] = W[(size_t)(r0 + r) * DMODEL + c0 + tx];
  }
  __syncthreads();
#pragma unroll
  for (int i = 0; i < 16; ++i) {
    const int r = ty + i * 4;
    T[(size_t)(c0 + r) * DMODEL + r0 + tx] = (bf16_t)tile[tx][r];
  }
}

// -------------------------------------- V [bh][2048][128] -> VT [bh][128][2048] bf16
__global__ __launch_bounds__(256) void transpose_v(const bf16_t* __restrict__ V,
                                                   bf16_t* __restrict__ VT) {
  __shared__ bf16_t tile[64 * 64];   // XOR-swizzled 64x64 tile
  const int bh = blockIdx.z;
  const int s0 = blockIdx.x * 64;
  const int d0 = blockIdx.y * 64;
  const bf16_t* src = V + ((size_t)bh * S_LEN + s0) * DHEAD + d0;
#pragma unroll
  for (int i = 0; i < 2; ++i) {
    const int v = threadIdx.x + i * 256;     // 0..511
    const int r = v >> 3, ch = v & 7;
    *(bf16x8*)&tile[r * 64 + ((ch ^ ((r >> 3) & 7)) << 3)] =
        *(const bf16x8*)(src + (size_t)r * DHEAD + ch * 8);
  }
  __syncthreads();
  bf16_t* dst = VT + ((size_t)bh * DHEAD + d0) * S_LEN + s0;
#pragma unroll
  for (int i = 0; i < 2; ++i) {
    const int v = threadIdx.x + i * 256;
    const int d = v >> 3, j = v & 7;         // out row d, col block j
    bf16x8 o;
#pragma unroll
    for (int e = 0; e < 8; ++e) {
      const int row = j * 8 + e;
      o[e] = tile[row * 64 + (((d >> 3) ^ j) << 3) + (d & 7)];
    }
    *(bf16x8*)(dst + (size_t)d * S_LEN + j * 8) = o;
  }
}

// ============== m201-faithful QKV GEMM: 256x256, BK=64, 4 phases/K-tile ==========
// 512 thr = 8 waves (2m x 4n), per-wave 128x64 out, acc[8][4] f32x4.
// LDS 2 buf x 64KB; buffer = {A-h0,A-h1,B-h0,B-h1} units of [128][64] (16KB each).
// Stage unit = 2 gload_lds/thread, linear dest, inverse-swizzled source
// (chunk ^= row&7; zero-conflict proven R4/R6). One unit staged PER PHASE:
//   q0: A-h0(t+1)  q1: A-h1(t+1)  q2: B-h0(t+2)  q3: B-h1(t+2)
// (A-halves -> opposite buffer, dead since prev tile's q2; B-halves -> own
//  buffer, dead after q1.) Register reuse: A-frags live 2 phases, B-frags live
// q0->q2 / q1->q3 => 24 ds_read_b128 per tile/wave for 64 MFMA.
// Counted vmcnt(4) once per tile at q3 (forces t+1 landed, leaves t+2.B);
// vmcnt(0) only at t>=30.
__global__ __launch_bounds__(512, 2) void gemm_qkv(
    const bf16_t* __restrict__ Xb,
    const bf16_t* __restrict__ WqT, const bf16_t* __restrict__ WkT,
    const bf16_t* __restrict__ WvT,
    const float* __restrict__ bq, const float* __restrict__ bk,
    const float* __restrict__ bv,
    bf16_t* __restrict__ Qg, bf16_t* __restrict__ Kg, bf16_t* __restrict__ Vg) {
  __shared__ __align__(16) char lds[2][65536];   // 128 KB

  const int tid  = threadIdx.x;
  const int lane = tid & 63;
  const int w    = tid >> 6;
  const int g    = lane >> 4;
  const int l16  = lane & 15;
  const int wm   = w >> 2;      // 0..1
  const int wn   = w & 3;       // 0..3
  const int NT   = DMODEL / 64; // 32

  // bijective XCD swizzle: nwg=384, 48 per XCD
  const int bid = blockIdx.x;
  const int wg  = (bid & 7) * 48 + (bid >> 3);
  const int mi  = wg / 24;
  const int ni  = wg % 24;
  const int z0  = ni >> 3;
  const bf16_t* Bt = (z0 == 0) ? WqT : (z0 == 1) ? WkT : WvT;
  const bf16_t* Abase = Xb + (size_t)mi * 256 * DMODEL;
  const bf16_t* Bbase = Bt + (size_t)(ni & 7) * 256 * DMODEL;

  f32x4 acc[8][4];
#pragma unroll
  for (int i = 0; i < 8; ++i)
#pragma unroll
    for (int j = 0; j < 4; ++j) acc[i][j] = (f32x4){0.f, 0.f, 0.f, 0.f};

  // stage one [128][64] unit (16KB): 2 loads/thread
  auto stage = [&](int tile, int mat, int half) {
    if (tile >= NT) return;
    const bf16_t* gb = (mat ? Bbase : Abase) + (size_t)(half * 128) * DMODEL + tile * 64;
    char* unit = &lds[tile & 1][0] + mat * 32768 + half * 16384;
#pragma unroll
    for (int jj = 0; jj < 2; ++jj) {
      const int c   = jj * 512 + tid;     // 0..1023
      const int row = c >> 3;             // 0..127 (8 x 16B chunks per 128B row)
      const int ch  = c & 7;
      gload_lds16(gb + (size_t)row * DMODEL + ((ch ^ (row & 7)) << 3),
                  unit + (jj * 512 + (tid & ~63)) * 16);
    }
  };

  // prologue: tile0 all 4 units + tile1 B-halves (t1's A-halves staged at t=0 q0/q1)
  stage(0, 0, 0); stage(0, 0, 1); stage(0, 1, 0); stage(0, 1, 1);
  stage(1, 1, 0); stage(1, 1, 1);
  asm volatile("s_waitcnt vmcnt(4)" ::: "memory");   // t0 landed, t1.B in flight
  __builtin_amdgcn_s_barrier();

  bf16x8 af[4][2], bn0[2][2], bn1[2][2];
  for (int t = 0; t < NT; ++t) {
    const char* bufA = &lds[t & 1][0] + wm * 16384;
    const char* bufB = &lds[t & 1][0] + 32768 + (wn >> 1) * 16384;

    // ---- q0: readA(mq=0) + readB(nq=0); stage A-h0(t+1)
#pragma unroll
    for (int i = 0; i < 4; ++i) {
      const int row = i * 16 + l16;
      const char* rp = bufA + row * 128;
#pragma unroll
      for (int ks = 0; ks < 2; ++ks)
        af[i][ks] = *(const bf16x8*)(rp + ((((ks << 2) | g) ^ (row & 7)) << 4));
    }
#pragma unroll
    for (int j = 0; j < 2; ++j) {
      const int row = (wn & 1) * 64 + j * 16 + l16;
      const char* rp = bufB + row * 128;
#pragma unroll
      for (int ks = 0; ks < 2; ++ks)
        bn0[j][ks] = *(const bf16x8*)(rp + ((((ks << 2) | g) ^ (row & 7)) << 4));
    }
    stage(t + 1, 0, 0);
    __builtin_amdgcn_s_barrier();
    asm volatile("s_waitcnt lgkmcnt(0)" ::: "memory");
    __builtin_amdgcn_s_setprio(1);
#pragma unroll
    for (int i = 0; i < 4; ++i)
#pragma unroll
      for (int j = 0; j < 2; ++j) {
        acc[i][j] = MFMA_BF16(af[i][0], bn0[j][0], acc[i][j]);
        acc[i][j] = MFMA_BF16(af[i][1], bn0[j][1], acc[i][j]);
      }
    __builtin_amdgcn_s_setprio(0);
    __builtin_amdgcn_s_barrier();

    // ---- q1: readB(nq=1); stage A-h1(t+1)
#pragma unroll
    for (int j = 0; j < 2; ++j) {
      const int row = (wn & 1) * 64 + 32 + j * 16 + l16;
      const char* rp = bufB + row * 128;
#pragma unroll
      for (int ks = 0; ks < 2; ++ks)
        bn1[j][ks] = *(const bf16x8*)(rp + ((((ks << 2) | g) ^ (row & 7)) << 4));
    }
    stage(t + 1, 0, 1);
    __builtin_amdgcn_s_barrier();
    asm volatile("s_waitcnt lgkmcnt(0)" ::: "memory");
    __builtin_amdgcn_s_setprio(1);
#pragma unroll
    for (int i = 0; i < 4; ++i)
#pragma unroll
      for (int j = 0; j < 2; ++j) {
        acc[i][j + 2] = MFMA_BF16(af[i][0], bn1[j][0], acc[i][j + 2]);
        acc[i][j + 2] = MFMA_BF16(af[i][1], bn1[j][1], acc[i][j + 2]);
      }
    __builtin_amdgcn_s_setprio(0);
    __builtin_amdgcn_s_barrier();

    // ---- q2: readA(mq=1); stage B-h0(t+2)
#pragma unroll
    for (int i = 0; i < 4; ++i) {
      const int row = 64 + i * 16 + l16;
      const char* rp = bufA + row * 128;
#pragma unroll
      for (int ks = 0; ks < 2; ++ks)
        af[i][ks] = *(const bf16x8*)(rp + ((((ks << 2) | g) ^ (row & 7)) << 4));
    }
    stage(t + 2, 1, 0);
    __builtin_amdgcn_s_barrier();
    asm volatile("s_waitcnt lgkmcnt(0)" ::: "memory");
    __builtin_amdgcn_s_setprio(1);
#pragma unroll
    for (int i = 0; i < 4; ++i)
#pragma unroll
      for (int j = 0; j < 2; ++j) {
        acc[i + 4][j] = MFMA_BF16(af[i][0], bn0[j][0], acc[i + 4][j]);
        acc[i + 4][j] = MFMA_BF16(af[i][1], bn0[j][1], acc[i + 4][j]);
      }
    __builtin_amdgcn_s_setprio(0);
    __builtin_amdgcn_s_barrier();

    // ---- q3: no reads; stage B-h1(t+2); counted vmcnt
    stage(t + 2, 1, 1);
    __builtin_amdgcn_s_setprio(1);
#pragma unroll
    for (int i = 0; i < 4; ++i)
#pragma unroll
      for (int j = 0; j < 2; ++j) {
        acc[i + 4][j + 2] = MFMA_BF16(af[i][0], bn1[j][0], acc[i + 4][j + 2]);
        acc[i + 4][j + 2] = MFMA_BF16(af[i][1], bn1[j][1], acc[i + 4][j + 2]);
      }
    __builtin_amdgcn_s_setprio(0);
    if (t < NT - 2) asm volatile("s_waitcnt vmcnt(4)" ::: "memory");
    else            asm volatile("s_waitcnt vmcnt(0)" ::: "memory");
    __builtin_amdgcn_s_barrier();
  }

  // epilogue: bias + scatter to [B,H,S,D] bf16 (verified in R6)
  const float* bias = (z0 == 0) ? bq : (z0 == 1) ? bk : bv;
  bf16_t* outb      = (z0 == 0) ? Qg : (z0 == 1) ? Kg : Vg;
#pragma unroll
  for (int i = 0; i < 8; ++i) {
#pragma unroll
    for (int j = 0; j < 4; ++j) {
      const int nloc = (ni & 7) * 256 + wn * 64 + j * 16 + l16;  // 0..2047
      const float bb = bias[nloc];
      const int h = nloc >> 7, d = nloc & (DHEAD - 1);
#pragma unroll
      for (int r = 0; r < 4; ++r) {
        const int mrow = mi * 256 + wm * 128 + i * 16 + g * 4 + r;
        const int b = mrow >> 11, s = mrow & (S_LEN - 1);
        outb[((size_t)(b * NHEADS + h) * S_LEN + s) * DHEAD + d] =
            (bf16_t)(acc[i][j][r] + bb);
      }
    }
  }
}

// ------------------------------------------- R4 GEMM body (gemm_out; proven)
template <int MODE>
__device__ __forceinline__ void gemm8_body(const bf16_t* __restrict__ A,
                                           const bf16_t* __restrict__ Bt,
                                           const float* __restrict__ bias,
                                           void* __restrict__ out) {
  __shared__ __align__(16) char lds8[2 * 49152];   // 96 KB
  const int tid  = threadIdx.x;
  const int lane = tid & 63;
  const int w    = tid >> 6;
  const int g    = lane >> 4;
  const int l16  = lane & 15;
  const int wm   = w >> 2;       // 0..1
  const int wn   = w & 3;        // 0..3
  const int m0   = blockIdx.y * 128;
  const int n0   = blockIdx.x * 256;

  f32x4 acc[4][4];
#pragma unroll
  for (int i = 0; i < 4; ++i)
#pragma unroll
    for (int j = 0; j < 4; ++j) acc[i][j] = (f32x4){0.f, 0.f, 0.f, 0.f};

  const int st_r0 = tid >> 3;
  const int st_ch = tid & 7;

  auto stage = [&](int tile, int r) {
    if (tile >= DMODEL / 64) return;
    const int kt = tile << 6;
    char* db = lds8 + (tile & 1) * 49152 + r * 16384 + w * 1024;
    const bf16_t* sb = (r == 0) ? (A + (size_t)m0 * DMODEL + kt)
                                : (Bt + (size_t)(n0 + ((r - 1) << 7)) * DMODEL + kt);
#pragma unroll
    for (int jj = 0; jj < 2; ++jj) {
      const int row = jj * 64 + st_r0;
      gload_lds16(sb + (size_t)row * DMODEL + ((st_ch ^ (row & 7)) << 3),
                  db + jj * 8192);
    }
  };

  stage(0, 0); stage(0, 1); stage(0, 2); stage(1, 0);
  asm volatile("s_waitcnt vmcnt(2)" ::: "memory");
  __builtin_amdgcn_s_barrier();

#pragma unroll 2
  for (int t = 0; t < DMODEL / 64; ++t) {
    const char* cb = lds8 + (t & 1) * 49152;
    bf16x8 af[4][2], b0[2][2], b1[2][2];
#pragma unroll
    for (int i = 0; i < 4; ++i) {
      const int row = wm * 64 + i * 16 + l16;
      const char* rp = cb + row * 128;
#pragma unroll
      for (int ks = 0; ks < 2; ++ks)
        af[i][ks] = *(const bf16x8*)(rp + ((((ks << 2) | g) ^ (row & 7)) << 4));
    }
#pragma unroll
    for (int j = 0; j < 2; ++j) {
      const int row = (wn & 1) * 64 + j * 16 + l16;
      const char* rp = cb + 16384 + (wn >> 1) * 16384 + row * 128;
#pragma unroll
      for (int ks = 0; ks < 2; ++ks)
        b0[j][ks] = *(const bf16x8*)(rp + ((((ks << 2) | g) ^ (row & 7)) << 4));
    }
    stage(t + 1, 1); stage(t + 1, 2);
    __builtin_amdgcn_s_barrier();
    asm volatile("s_waitcnt lgkmcnt(0)" ::: "memory");
    __builtin_amdgcn_s_setprio(1);
#pragma unroll
    for (int i = 0; i < 4; ++i)
#pragma unroll
      for (int j = 0; j < 2; ++j) {
        acc[i][j] = MFMA_BF16(af[i][0], b0[j][0], acc[i][j]);
        acc[i][j] = MFMA_BF16(af[i][1], b0[j][1], acc[i][j]);
      }
    __builtin_amdgcn_s_setprio(0);
    __builtin_amdgcn_s_barrier();
#pragma unroll
    for (int j = 0; j < 2; ++j) {
      const int row = (wn & 1) * 64 + (j + 2) * 16 + l16;
      const char* rp = cb + 16384 + (wn >> 1) * 16384 + row * 128;
#pragma unroll
      for (int ks = 0; ks < 2; ++ks)
        b1[j][ks] = *(const bf16x8*)(rp + ((((ks << 2) | g) ^ (row & 7)) << 4));
    }
    stage(t + 2, 0);
    __builtin_amdgcn_s_barrier();
    asm volatile("s_waitcnt lgkmcnt(0)" ::: "memory");
    __builtin_amdgcn_s_setprio(1);
#pragma unroll
    for (int i = 0; i < 4; ++i)
#pragma unroll
      for (int j = 0; j < 2; ++j) {
        acc[i][j + 2] = MFMA_BF16(af[i][0], b1[j][0], acc[i][j + 2]);
        acc[i][j + 2] = MFMA_BF16(af[i][1], b1[j][1], acc[i][j + 2]);
      }
    __builtin_amdgcn_s_setprio(0);
    if (t < DMODEL / 64 - 2) asm volatile("s_waitcnt vmcnt(2)" ::: "memory");
    else                     asm volatile("s_waitcnt vmcnt(0)" ::: "memory");
    __builtin_amdgcn_s_barrier();
  }

#pragma unroll
  for (int i = 0; i < 4; ++i) {
#pragma unroll
    for (int j = 0; j < 4; ++j) {
      const int n    = n0 + wn * 64 + j * 16 + l16;
      const float bb = bias[n];
#pragma unroll
      for (int r = 0; r < 4; ++r) {
        const int m   = m0 + wm * 64 + i * 16 + g * 4 + r;
        const float v = acc[i][j][r] + bb;
        if (MODE == 0) {
          const int b = m >> 11, s = m & (S_LEN - 1);
          const int h = n >> 7,  d = n & (DHEAD - 1);
          ((bf16_t*)out)[((size_t)(b * NHEADS + h) * S_LEN + s) * DHEAD + d] = (bf16_t)v;
        } else {
          ((float*)out)[(size_t)m * DMODEL + n] = v;
        }
      }
    }
  }
}

__global__ __launch_bounds__(512, 2) void gemm_out(
    const bf16_t* __restrict__ Ctx, const bf16_t* __restrict__ WoT,
    const float* __restrict__ bo, float* __restrict__ out) {
  gemm8_body<1>(Ctx, WoT, bo, out);
}

// --------------------------------------------------------------- flash attention
// (R7 version — proven fastest: direct global_load_lds staging)
#define KTILE_B 16384
#define VTILE_B 16384
#define ABUF_B  (KTILE_B + VTILE_B)   // 32 KB per buffer

__global__ __launch_bounds__(256, 2) void attn_kernel(
    const bf16_t* __restrict__ Qg, const bf16_t* __restrict__ Kg,
    const bf16_t* __restrict__ VTg, bf16_t* __restrict__ ctx) {
  __shared__ __align__(16) char ldsbuf[2][ABUF_B];
  __shared__ float lbuf[4][32];

  const int tid  = threadIdx.x;
  const int lane = tid & 63;
  const int w    = tid >> 6;
  const int l31  = lane & 31;
  const int hi   = lane >> 5;

  const int id   = blockIdx.x;                  // 512 blocks
  const int bh   = id & 31;
  const int jraw = id >> 5;
  const int j    = (jraw < 8) ? jraw : 23 - jraw;   // pair (j,15-j) co-resident
  const int q0   = j * 128;
  const int qw   = q0 + w * 32;
  const int tq   = (qw + 31) >> 6;              // diagonal tile index for this wave
  const int NT   = (q0 + 128) >> 6;             // tiles this block processes

  const size_t bho = (size_t)bh * S_LEN * DHEAD;
  const bf16_t* Qb  = Qg + bho;
  const bf16_t* Kb  = Kg + bho;
  const bf16_t* VTb = VTg + bho;                // [128][2048]

  auto stageT = [&](int t) {
    const int kt = t << 6;
    char* dst = ldsbuf[t & 1];
#pragma unroll
    for (int i = 0; i < 4; ++i) {                 // K: 64 rows x 256B
      const int c   = i * 256 + tid;              // 0..1023
      const int row = c >> 4, ch = c & 15;
      gload_lds16(Kb + (size_t)(kt + row) * DHEAD + ((ch ^ (row & 7)) << 3),
                  dst + (i * 256 + (tid & ~63)) * 16);
    }
#pragma unroll
    for (int i = 0; i < 4; ++i) {                 // VT: 128 rows x 128B
      const int c   = i * 256 + tid;
      const int row = c >> 3, ch = c & 7;
      gload_lds16(VTb + (size_t)row * S_LEN + kt + ((ch ^ (row & 7)) << 3),
                  dst + KTILE_B + (i * 256 + (tid & ~63)) * 16);
    }
  };

  bf16x8 qreg[8];
#pragma unroll
  for (int s = 0; s < 8; ++s)
    qreg[s] = *(const bf16x8*)(Qb + (size_t)(qw + l31) * DHEAD + s * 16 + hi * 8);

  f32x16 oacc[4];
#pragma unroll
  for (int d0 = 0; d0 < 4; ++d0)
#pragma unroll
    for (int e = 0; e < 16; ++e) oacc[d0][e] = 0.f;

  float m = -1e30f, lsum = 0.f;
  const float sc2 = 0.12751751135f;             // log2(e)/sqrt(128)

  stageT(0);
  asm volatile("s_waitcnt vmcnt(0)" ::: "memory");
  __syncthreads();

  for (int t = 0; t < NT; ++t) {
    const char* bK = ldsbuf[t & 1];
    const char* bV = bK + KTILE_B;
    if (t + 1 < NT) stageT(t + 1);

    if (t <= tq) {
      const int kt = t << 6;
      f32x16 stt[2];
#pragma unroll
      for (int kh = 0; kh < 2; ++kh)
#pragma unroll
        for (int e = 0; e < 16; ++e) stt[kh][e] = 0.f;
#pragma unroll
      for (int kh = 0; kh < 2; ++kh) {
        const int row = kh * 32 + l31;
        const char* rb = bK + row * 256;
        const int swz = (row & 7) << 4;
#pragma unroll
        for (int s = 0; s < 8; ++s) {
          const bf16x8 kf = *(const bf16x8*)(rb + ((((s << 1) | hi) << 4) ^ swz));
          stt[kh] = MFMA32(kf, qreg[s], stt[kh]);
        }
      }
      if (t == tq) {
        const int qg = qw + l31;
#pragma unroll
        for (int kh = 0; kh < 2; ++kh)
#pragma unroll
          for (int r = 0; r < 16; ++r) {
            const int kv = kt + kh * 32 + (r & 3) + 8 * (r >> 2) + 4 * hi;
            stt[kh][r] = (kv > qg) ? -1e30f : stt[kh][r];
          }
      }
      float pm = stt[0][0];
#pragma unroll
      for (int kh = 0; kh < 2; ++kh)
#pragma unroll
        for (int r = 0; r < 16; ++r)
          if (kh | r) pm = fmaxf(pm, stt[kh][r]);
      pm = fmaxf(pm, __shfl_xor(pm, 32));
      const float pmax = pm * sc2;
      if (!__all(pmax <= m + 8.f)) {
        const float mn   = fmaxf(m, pmax);
        const float corr = __builtin_amdgcn_exp2f(m - mn);
        m = mn;
        lsum *= corr;
        if (!hi) lbuf[w][l31] = corr;
#pragma unroll
        for (int r = 0; r < 16; ++r) {
          const float cr = lbuf[w][(r & 3) + 8 * (r >> 2) + 4 * hi];
#pragma unroll
          for (int d0 = 0; d0 < 4; ++d0) oacc[d0][r] *= cr;
        }
      }
      float rs = 0.f;
#pragma unroll
      for (int kh = 0; kh < 2; ++kh)
#pragma unroll
        for (int r = 0; r < 16; ++r) {
          const float p = __builtin_amdgcn_exp2f(__builtin_fmaf(stt[kh][r], sc2, -m));
          stt[kh][r] = p;
          rs += p;
        }
      rs += __shfl_xor(rs, 32);
      lsum += rs;
      unsigned pw_[2][8];
#pragma unroll
      for (int kh = 0; kh < 2; ++kh)
#pragma unroll
        for (int jj = 0; jj < 8; ++jj)
          pw_[kh][jj] = pk2(stt[kh][2 * jj], stt[kh][2 * jj + 1]);
      bf16x8 pa[4];
#pragma unroll
      for (int kh = 0; kh < 2; ++kh)
#pragma unroll
        for (int c2 = 0; c2 < 2; ++c2) {
          const unsigned o0 = pw_[kh][4 * c2 + 0], o1 = pw_[kh][4 * c2 + 1];
          const unsigned o2 = pw_[kh][4 * c2 + 2], o3 = pw_[kh][4 * c2 + 3];
          const unsigned p0 = (unsigned)__shfl_xor((int)o0, 32);
          const unsigned p1 = (unsigned)__shfl_xor((int)o1, 32);
          const unsigned p2 = (unsigned)__shfl_xor((int)o2, 32);
          const unsigned p3 = (unsigned)__shfl_xor((int)o3, 32);
          union { unsigned u[4]; bf16x8 v; } uu;
          uu.u[0] = hi ? p2 : o0;
          uu.u[1] = hi ? p3 : o1;
          uu.u[2] = hi ? o2 : p0;
          uu.u[3] = hi ? o3 : p1;
          pa[2 * kh + c2] = uu.v;
        }
#pragma unroll
      for (int d0 = 0; d0 < 4; ++d0) {
        const int row = d0 * 32 + l31;
        const char* rb = bV + row * 128;
        const int swz = (row & 7) << 4;
#pragma unroll
        for (int ks = 0; ks < 4; ++ks) {
          const bf16x8 vb = *(const bf16x8*)(rb + ((((ks << 1) | hi) << 4) ^ swz));
          oacc[d0] = MFMA32(pa[ks], vb, oacc[d0]);
        }
      }
    }
    asm volatile("s_waitcnt vmcnt(0)" ::: "memory");
    __syncthreads();
  }

  if (!hi) lbuf[w][l31] = 1.0f / lsum;
  const int b = bh >> 4, h = bh & 15;
#pragma unroll
  for (int r = 0; r < 16; ++r) {
    const int cro = (r & 3) + 8 * (r >> 2) + 4 * hi;
    const float li = lbuf[w][cro];
    const size_t base = ((size_t)(b * S_LEN + qw + cro)) * DMODEL + h * DHEAD;
#pragma unroll
    for (int d0 = 0; d0 < 4; ++d0)
      ctx[base + d0 * 32 + l31] = (bf16_t)(oacc[d0][r] * li);
  }
}

// ------------------------------------------------------------------------- launch
extern "C" void kernel_launch(void* const* d_in, const int* in_sizes, int n_in,
                              void* d_out, int out_size, void* d_ws, size_t ws_size,
                              hipStream_t stream) {
  const float* x  = (const float*)d_in[0];
  const float* Wq = (const float*)d_in[1];
  const float* bq = (const float*)d_in[2];
  const float* Wk = (const float*)d_in[3];
  const float* bk = (const float*)d_in[4];
  const float* Wv = (const float*)d_in[5];
  const float* bv = (const float*)d_in[6];
  const float* Wo = (const float*)d_in[7];
  const float* bo = (const float*)d_in[8];

  char* ws = (char*)d_ws;
  const size_t MB = 1ull << 20;
  bf16_t* Xb  = (bf16_t*)(ws + 0);          // x bf16 (dead after gemm_qkv)
  bf16_t* VTg = (bf16_t*)(ws + 0);          // V^T reuses Xb's slot
  bf16_t* WqT = (bf16_t*)(ws + 16 * MB);
  bf16_t* WkT = (bf16_t*)(ws + 24 * MB);
  bf16_t* WvT = (bf16_t*)(ws + 32 * MB);
  bf16_t* WoT = (bf16_t*)(ws + 40 * MB);
  bf16_t* Qg  = (bf16_t*)(ws + 48 * MB);
  bf16_t* Kg  = (bf16_t*)(ws + 64 * MB);
  bf16_t* Vg  = (bf16_t*)(ws + 80 * MB);
  bf16_t* Ctx = (bf16_t*)(ws + 96 * MB);
  if (ws_size < 112 * MB) return;

  cast_kernel<<<dim3(MROWS * DMODEL / (256 * 8)), 256, 0, stream>>>(x, Xb);
  transpose_cast<<<dim3(32, 32, 4), 256, 0, stream>>>(Wq, Wk, Wv, Wo, WqT, WkT, WvT, WoT);
  gemm_qkv<<<dim3(384), 512, 0, stream>>>(
      Xb, WqT, WkT, WvT, bq, bk, bv, Qg, Kg, Vg);
  transpose_v<<<dim3(32, 2, 32), 256, 0, stream>>>(Vg, VTg);
  attn_kernel<<<dim3(512), 256, 0, stream>>>(Qg, Kg, VTg, Ctx);
  gemm_out<<<dim3(DMODEL / 256, MROWS / 128), 512, 0, stream>>>(Ctx, WoT, bo, (float*)d_out);
}

// Round 11
// 220.528 us; speedup vs baseline: 1.1210x; 1.0889x over previous
//
#include <hip/hip_runtime.h>
#include <hip/hip_bf16.h>
#include <stdint.h>

#define S_LEN  2048
#define DMODEL 2048
#define NHEADS 16
#define DHEAD  128
#define NBATCH 2
#define MROWS  (NBATCH * S_LEN)   // 4096

typedef __bf16 bf16_t;
typedef __bf16 bf16x8 __attribute__((ext_vector_type(8)));
typedef float  f32x4  __attribute__((ext_vector_type(4)));
typedef float  f32x16 __attribute__((ext_vector_type(16)));

#define MFMA_BF16(A, B, C) __builtin_amdgcn_mfma_f32_16x16x32_bf16((A), (B), (C), 0, 0, 0)
#define MFMA32(A, B, C)    __builtin_amdgcn_mfma_f32_32x32x16_bf16((A), (B), (C), 0, 0, 0)

__device__ __forceinline__ void gload_lds16(const void* g, void* l) {
  __builtin_amdgcn_global_load_lds(
      (__attribute__((address_space(1))) uint32_t*)(uintptr_t)g,
      (__attribute__((address_space(3))) uint32_t*)l,
      16, 0, 0);
}

__device__ __forceinline__ unsigned pk2(float lo, float hi) {
  const unsigned short a = __builtin_bit_cast(unsigned short, (bf16_t)lo);
  const unsigned short b = __builtin_bit_cast(unsigned short, (bf16_t)hi);
  return (unsigned)a | ((unsigned)b << 16);
}

// ---------------------------------------------------------------- cast x -> bf16
__global__ __launch_bounds__(256) void cast_kernel(const float* __restrict__ X,
                                                   bf16_t* __restrict__ Xb) {
  const int i = blockIdx.x * 256 + threadIdx.x;
  const f32x4 a = ((const f32x4*)X)[2 * i];
  const f32x4 b = ((const f32x4*)X)[2 * i + 1];
  bf16x8 o;
#pragma unroll
  for (int j = 0; j < 4; ++j) { o[j] = (bf16_t)a[j]; o[j + 4] = (bf16_t)b[j]; }
  ((bf16x8*)Xb)[i] = o;
}

// ---------------------------------------------------- W [K][N] f32 -> Wt [N][K] bf16
__global__ __launch_bounds__(256) void transpose_cast(
    const float* __restrict__ W0, const float* __restrict__ W1,
    const float* __restrict__ W2, const float* __restrict__ W3,
    bf16_t* __restrict__ T0, bf16_t* __restrict__ T1,
    bf16_t* __restrict__ T2, bf16_t* __restrict__ T3) {
  const float* W; bf16_t* T;
  switch (blockIdx.z) {
    case 0:  W = W0; T = T0; break;
    case 1:  W = W1; T = T1; break;
    case 2:  W = W2; T = T2; break;
    default: W = W3; T = T3; break;
  }
  __shared__ float tile[64][65];
  const int r0 = blockIdx.y * 64;
  const int c0 = blockIdx.x * 64;
  const int tx = threadIdx.x & 63;
  const int ty = threadIdx.x >> 6;
#pragma unroll
  for (int i = 0; i < 16; ++i) {
    const int r = ty + i * 4;
    tile[r][tx] = W[(size_t)(r0 + r) * DMODEL + c0 + tx];
  }
  __syncthreads();
#pragma unroll
  for (int i = 0; i < 16; ++i) {
    const int r = ty + i * 4;
    T[(size_t)(c0 + r) * DMODEL + r0 + tx] = (bf16_t)tile[tx][r];
  }
}

// ------------------------------------------- R4 GEMM body: BM=128 BN=256 BK=64
// Proven main loop (0 conflicts, MfmaUtil 38%). Epilogue by mode:
//   mode 0: bf16 scatter to [B,H,S,D]   (Q,K)
//   mode 1: f32 row-major [M][2048]     (out-proj)
//   mode 2: LDS-transpose -> VT [bh][d][s] bf16 (V)
__device__ __forceinline__ void gemm8_body(const bf16_t* __restrict__ A,
                                           const bf16_t* __restrict__ Bt,
                                           const float* __restrict__ bias,
                                           void* __restrict__ out,
                                           int m0, int n0, int mode) {
  __shared__ __align__(16) char lds8[2 * 49152];   // 96 KB
  const int tid  = threadIdx.x;
  const int lane = tid & 63;
  const int w    = tid >> 6;
  const int g    = lane >> 4;
  const int l16  = lane & 15;
  const int wm   = w >> 2;       // 0..1
  const int wn   = w & 3;        // 0..3

  f32x4 acc[4][4];
#pragma unroll
  for (int i = 0; i < 4; ++i)
#pragma unroll
    for (int j = 0; j < 4; ++j) acc[i][j] = (f32x4){0.f, 0.f, 0.f, 0.f};

  const int st_r0 = tid >> 3;
  const int st_ch = tid & 7;

  auto stage = [&](int tile, int r) {
    if (tile >= DMODEL / 64) return;
    const int kt = tile << 6;
    char* db = lds8 + (tile & 1) * 49152 + r * 16384 + w * 1024;
    const bf16_t* sb = (r == 0) ? (A + (size_t)m0 * DMODEL + kt)
                                : (Bt + (size_t)(n0 + ((r - 1) << 7)) * DMODEL + kt);
#pragma unroll
    for (int jj = 0; jj < 2; ++jj) {
      const int row = jj * 64 + st_r0;
      gload_lds16(sb + (size_t)row * DMODEL + ((st_ch ^ (row & 7)) << 3),
                  db + jj * 8192);
    }
  };

  stage(0, 0); stage(0, 1); stage(0, 2); stage(1, 0);
  asm volatile("s_waitcnt vmcnt(2)" ::: "memory");
  __builtin_amdgcn_s_barrier();

#pragma unroll 2
  for (int t = 0; t < DMODEL / 64; ++t) {
    const char* cb = lds8 + (t & 1) * 49152;
    bf16x8 af[4][2], b0[2][2], b1[2][2];
#pragma unroll
    for (int i = 0; i < 4; ++i) {
      const int row = wm * 64 + i * 16 + l16;
      const char* rp = cb + row * 128;
#pragma unroll
      for (int ks = 0; ks < 2; ++ks)
        af[i][ks] = *(const bf16x8*)(rp + ((((ks << 2) | g) ^ (row & 7)) << 4));
    }
#pragma unroll
    for (int j = 0; j < 2; ++j) {
      const int row = (wn & 1) * 64 + j * 16 + l16;
      const char* rp = cb + 16384 + (wn >> 1) * 16384 + row * 128;
#pragma unroll
      for (int ks = 0; ks < 2; ++ks)
        b0[j][ks] = *(const bf16x8*)(rp + ((((ks << 2) | g) ^ (row & 7)) << 4));
    }
    stage(t + 1, 1); stage(t + 1, 2);
    __builtin_amdgcn_s_barrier();
    asm volatile("s_waitcnt lgkmcnt(0)" ::: "memory");
    __builtin_amdgcn_s_setprio(1);
#pragma unroll
    for (int i = 0; i < 4; ++i)
#pragma unroll
      for (int j = 0; j < 2; ++j) {
        acc[i][j] = MFMA_BF16(af[i][0], b0[j][0], acc[i][j]);
        acc[i][j] = MFMA_BF16(af[i][1], b0[j][1], acc[i][j]);
      }
    __builtin_amdgcn_s_setprio(0);
    __builtin_amdgcn_s_barrier();
#pragma unroll
    for (int j = 0; j < 2; ++j) {
      const int row = (wn & 1) * 64 + (j + 2) * 16 + l16;
      const char* rp = cb + 16384 + (wn >> 1) * 16384 + row * 128;
#pragma unroll
      for (int ks = 0; ks < 2; ++ks)
        b1[j][ks] = *(const bf16x8*)(rp + ((((ks << 2) | g) ^ (row & 7)) << 4));
    }
    stage(t + 2, 0);
    __builtin_amdgcn_s_barrier();
    asm volatile("s_waitcnt lgkmcnt(0)" ::: "memory");
    __builtin_amdgcn_s_setprio(1);
#pragma unroll
    for (int i = 0; i < 4; ++i)
#pragma unroll
      for (int j = 0; j < 2; ++j) {
        acc[i][j + 2] = MFMA_BF16(af[i][0], b1[j][0], acc[i][j + 2]);
        acc[i][j + 2] = MFMA_BF16(af[i][1], b1[j][1], acc[i][j + 2]);
      }
    __builtin_amdgcn_s_setprio(0);
    if (t < DMODEL / 64 - 2) asm volatile("s_waitcnt vmcnt(2)" ::: "memory");
    else                     asm volatile("s_waitcnt vmcnt(0)" ::: "memory");
    __builtin_amdgcn_s_barrier();
  }

  if (mode == 2) {
    // ---- V: transpose through LDS, write VT[bh][d][s] coalesced.
    // LDS layout: [n_local 256][m_local 128] bf16, row stride 136 elem (272B).
    bf16_t* tr = (bf16_t*)lds8;      // 256*136*2 = 69632 <= 98304
#pragma unroll
    for (int i = 0; i < 4; ++i) {
#pragma unroll
      for (int j = 0; j < 4; ++j) {
        const int nl = wn * 64 + j * 16 + l16;
        const int ml = wm * 64 + i * 16 + g * 4;
        const float bb = bias[n0 + nl];
        union { unsigned short u[4]; uint64_t v; } pk;
#pragma unroll
        for (int r = 0; r < 4; ++r)
          pk.u[r] = __builtin_bit_cast(unsigned short, (bf16_t)(acc[i][j][r] + bb));
        *(uint64_t*)&tr[nl * 136 + ml] = pk.v;
      }
    }
    __syncthreads();
    const int b = m0 >> 11;
    const int s0 = m0 & (S_LEN - 1);
#pragma unroll
    for (int it = 0; it < 8; ++it) {
      const int c   = it * 512 + tid;   // 0..4095 exactly (512 threads x 8)
      const int nl  = c >> 4;           // 0..255
      const int ml8 = c & 15;           // 0..15
      const bf16x8 v = *(const bf16x8*)&tr[nl * 136 + ml8 * 8];
      const int n  = n0 + nl;
      const int h  = n >> 7, dd = n & (DHEAD - 1);
      *(bf16x8*)((bf16_t*)out +
                 ((size_t)(b * NHEADS + h) * DHEAD + dd) * S_LEN + s0 + ml8 * 8) = v;
    }
    return;
  }

#pragma unroll
  for (int i = 0; i < 4; ++i) {
#pragma unroll
    for (int j = 0; j < 4; ++j) {
      const int n    = n0 + wn * 64 + j * 16 + l16;
      const float bb = bias[n];
#pragma unroll
      for (int r = 0; r < 4; ++r) {
        const int m   = m0 + wm * 64 + i * 16 + g * 4 + r;
        const float v = acc[i][j][r] + bb;
        if (mode == 0) {
          const int b = m >> 11, s = m & (S_LEN - 1);
          const int h = n >> 7,  d = n & (DHEAD - 1);
          ((bf16_t*)out)[((size_t)(b * NHEADS + h) * S_LEN + s) * DHEAD + d] = (bf16_t)v;
        } else {
          ((float*)out)[(size_t)m * DMODEL + n] = v;
        }
      }
    }
  }
}

// QKV: 1-D grid 768, bijective XCD swizzle (768 = 8 XCD x 96), work id x-fastest.
__global__ __launch_bounds__(512, 2) void gemm_qkv(
    const bf16_t* __restrict__ Xb,
    const bf16_t* __restrict__ WqT, const bf16_t* __restrict__ WkT,
    const bf16_t* __restrict__ WvT,
    const float* __restrict__ bq, const float* __restrict__ bk,
    const float* __restrict__ bv,
    bf16_t* __restrict__ Qg, bf16_t* __restrict__ Kg, bf16_t* __restrict__ VTg) {
  const int bid = blockIdx.x;
  const int wg  = (bid & 7) * 96 + (bid >> 3);   // XCD k runs wg in [96k, 96k+96)
  const int x   = wg & 7;
  const int y   = (wg >> 3) & 31;
  const int z0  = wg >> 8;
  const bf16_t* Bt  = (z0 == 0) ? WqT : (z0 == 1) ? WkT : WvT;
  const float* bias = (z0 == 0) ? bq  : (z0 == 1) ? bk  : bv;
  void* out         = (z0 == 0) ? (void*)Qg : (z0 == 1) ? (void*)Kg : (void*)VTg;
  gemm8_body(Xb, Bt, bias, out, y * 128, x * 256, (z0 == 2) ? 2 : 0);
}

__global__ __launch_bounds__(512, 2) void gemm_out(
    const bf16_t* __restrict__ Ctx, const bf16_t* __restrict__ WoT,
    const float* __restrict__ bo, float* __restrict__ out) {
  gemm8_body(Ctx, WoT, bo, out, blockIdx.y * 128, blockIdx.x * 256, 1);
}

// --------------------------------------------------------------- flash attention
// (R7 version — proven fastest: direct global_load_lds staging)
#define KTILE_B 16384
#define VTILE_B 16384
#define ABUF_B  (KTILE_B + VTILE_B)   // 32 KB per buffer

__global__ __launch_bounds__(256, 2) void attn_kernel(
    const bf16_t* __restrict__ Qg, const bf16_t* __restrict__ Kg,
    const bf16_t* __restrict__ VTg, bf16_t* __restrict__ ctx) {
  __shared__ __align__(16) char ldsbuf[2][ABUF_B];
  __shared__ float lbuf[4][32];

  const int tid  = threadIdx.x;
  const int lane = tid & 63;
  const int w    = tid >> 6;
  const int l31  = lane & 31;
  const int hi   = lane >> 5;

  const int id   = blockIdx.x;                  // 512 blocks
  const int bh   = id & 31;
  const int jraw = id >> 5;
  const int j    = (jraw < 8) ? jraw : 23 - jraw;   // pair (j,15-j) co-resident
  const int q0   = j * 128;
  const int qw   = q0 + w * 32;
  const int tq   = (qw + 31) >> 6;              // diagonal tile index for this wave
  const int NT   = (q0 + 128) >> 6;             // tiles this block processes

  const size_t bho = (size_t)bh * S_LEN * DHEAD;
  const bf16_t* Qb  = Qg + bho;
  const bf16_t* Kb  = Kg + bho;
  const bf16_t* VTb = VTg + bho;                // [128][2048]

  auto stageT = [&](int t) {
    const int kt = t << 6;
    char* dst = ldsbuf[t & 1];
#pragma unroll
    for (int i = 0; i < 4; ++i) {                 // K: 64 rows x 256B
      const int c   = i * 256 + tid;              // 0..1023
      const int row = c >> 4, ch = c & 15;
      gload_lds16(Kb + (size_t)(kt + row) * DHEAD + ((ch ^ (row & 7)) << 3),
                  dst + (i * 256 + (tid & ~63)) * 16);
    }
#pragma unroll
    for (int i = 0; i < 4; ++i) {                 // VT: 128 rows x 128B
      const int c   = i * 256 + tid;
      const int row = c >> 3, ch = c & 7;
      gload_lds16(VTb + (size_t)row * S_LEN + kt + ((ch ^ (row & 7)) << 3),
                  dst + KTILE_B + (i * 256 + (tid & ~63)) * 16);
    }
  };

  bf16x8 qreg[8];
#pragma unroll
  for (int s = 0; s < 8; ++s)
    qreg[s] = *(const bf16x8*)(Qb + (size_t)(qw + l31) * DHEAD + s * 16 + hi * 8);

  f32x16 oacc[4];
#pragma unroll
  for (int d0 = 0; d0 < 4; ++d0)
#pragma unroll
    for (int e = 0; e < 16; ++e) oacc[d0][e] = 0.f;

  float m = -1e30f, lsum = 0.f;
  const float sc2 = 0.12751751135f;             // log2(e)/sqrt(128)

  stageT(0);
  asm volatile("s_waitcnt vmcnt(0)" ::: "memory");
  __syncthreads();

  for (int t = 0; t < NT; ++t) {
    const char* bK = ldsbuf[t & 1];
    const char* bV = bK + KTILE_B;
    if (t + 1 < NT) stageT(t + 1);

    if (t <= tq) {
      const int kt = t << 6;
      f32x16 stt[2];
#pragma unroll
      for (int kh = 0; kh < 2; ++kh)
#pragma unroll
        for (int e = 0; e < 16; ++e) stt[kh][e] = 0.f;
#pragma unroll
      for (int kh = 0; kh < 2; ++kh) {
        const int row = kh * 32 + l31;
        const char* rb = bK + row * 256;
        const int swz = (row & 7) << 4;
#pragma unroll
        for (int s = 0; s < 8; ++s) {
          const bf16x8 kf = *(const bf16x8*)(rb + ((((s << 1) | hi) << 4) ^ swz));
          stt[kh] = MFMA32(kf, qreg[s], stt[kh]);
        }
      }
      if (t == tq) {
        const int qg = qw + l31;
#pragma unroll
        for (int kh = 0; kh < 2; ++kh)
#pragma unroll
          for (int r = 0; r < 16; ++r) {
            const int kv = kt + kh * 32 + (r & 3) + 8 * (r >> 2) + 4 * hi;
            stt[kh][r] = (kv > qg) ? -1e30f : stt[kh][r];
          }
      }
      float pm = stt[0][0];
#pragma unroll
      for (int kh = 0; kh < 2; ++kh)
#pragma unroll
        for (int r = 0; r < 16; ++r)
          if (kh | r) pm = fmaxf(pm, stt[kh][r]);
      pm = fmaxf(pm, __shfl_xor(pm, 32));
      const float pmax = pm * sc2;
      if (!__all(pmax <= m + 8.f)) {
        const float mn   = fmaxf(m, pmax);
        const float corr = __builtin_amdgcn_exp2f(m - mn);
        m = mn;
        lsum *= corr;
        if (!hi) lbuf[w][l31] = corr;
#pragma unroll
        for (int r = 0; r < 16; ++r) {
          const float cr = lbuf[w][(r & 3) + 8 * (r >> 2) + 4 * hi];
#pragma unroll
          for (int d0 = 0; d0 < 4; ++d0) oacc[d0][r] *= cr;
        }
      }
      float rs = 0.f;
#pragma unroll
      for (int kh = 0; kh < 2; ++kh)
#pragma unroll
        for (int r = 0; r < 16; ++r) {
          const float p = __builtin_amdgcn_exp2f(__builtin_fmaf(stt[kh][r], sc2, -m));
          stt[kh][r] = p;
          rs += p;
        }
      rs += __shfl_xor(rs, 32);
      lsum += rs;
      unsigned pw_[2][8];
#pragma unroll
      for (int kh = 0; kh < 2; ++kh)
#pragma unroll
        for (int jj = 0; jj < 8; ++jj)
          pw_[kh][jj] = pk2(stt[kh][2 * jj], stt[kh][2 * jj + 1]);
      bf16x8 pa[4];
#pragma unroll
      for (int kh = 0; kh < 2; ++kh)
#pragma unroll
        for (int c2 = 0; c2 < 2; ++c2) {
          const unsigned o0 = pw_[kh][4 * c2 + 0], o1 = pw_[kh][4 * c2 + 1];
          const unsigned o2 = pw_[kh][4 * c2 + 2], o3 = pw_[kh][4 * c2 + 3];
          const unsigned p0 = (unsigned)__shfl_xor((int)o0, 32);
          const unsigned p1 = (unsigned)__shfl_xor((int)o1, 32);
          const unsigned p2 = (unsigned)__shfl_xor((int)o2, 32);
          const unsigned p3 = (unsigned)__shfl_xor((int)o3, 32);
          union { unsigned u[4]; bf16x8 v; } uu;
          uu.u[0] = hi ? p2 : o0;
          uu.u[1] = hi ? p3 : o1;
          uu.u[2] = hi ? o2 : p0;
          uu.u[3] = hi ? o3 : p1;
          pa[2 * kh + c2] = uu.v;
        }
#pragma unroll
      for (int d0 = 0; d0 < 4; ++d0) {
        const int row = d0 * 32 + l31;
        const char* rb = bV + row * 128;
        const int swz = (row & 7) << 4;
#pragma unroll
        for (int ks = 0; ks < 4; ++ks) {
          const bf16x8 vb = *(const bf16x8*)(rb + ((((ks << 1) | hi) << 4) ^ swz));
          oacc[d0] = MFMA32(pa[ks], vb, oacc[d0]);
        }
      }
    }
    asm volatile("s_waitcnt vmcnt(0)" ::: "memory");
    __syncthreads();
  }

  if (!hi) lbuf[w][l31] = 1.0f / lsum;
  const int b = bh >> 4, h = bh & 15;
#pragma unroll
  for (int r = 0; r < 16; ++r) {
    const int cro = (r & 3) + 8 * (r >> 2) + 4 * hi;
    const float li = lbuf[w][cro];
    const size_t base = ((size_t)(b * S_LEN + qw + cro)) * DMODEL + h * DHEAD;
#pragma unroll
    for (int d0 = 0; d0 < 4; ++d0)
      ctx[base + d0 * 32 + l31] = (bf16_t)(oacc[d0][r] * li);
  }
}

// ------------------------------------------------------------------------- launch
extern "C" void kernel_launch(void* const* d_in, const int* in_sizes, int n_in,
                              void* d_out, int out_size, void* d_ws, size_t ws_size,
                              hipStream_t stream) {
  const float* x  = (const float*)d_in[0];
  const float* Wq = (const float*)d_in[1];
  const float* bq = (const float*)d_in[2];
  const float* Wk = (const float*)d_in[3];
  const float* bk = (const float*)d_in[4];
  const float* Wv = (const float*)d_in[5];
  const float* bv = (const float*)d_in[6];
  const float* Wo = (const float*)d_in[7];
  const float* bo = (const float*)d_in[8];

  char* ws = (char*)d_ws;
  const size_t MB = 1ull << 20;
  bf16_t* Xb  = (bf16_t*)(ws + 0);
  bf16_t* WqT = (bf16_t*)(ws + 16 * MB);
  bf16_t* WkT = (bf16_t*)(ws + 24 * MB);
  bf16_t* WvT = (bf16_t*)(ws + 32 * MB);
  bf16_t* WoT = (bf16_t*)(ws + 40 * MB);
  bf16_t* Qg  = (bf16_t*)(ws + 48 * MB);
  bf16_t* Kg  = (bf16_t*)(ws + 64 * MB);
  bf16_t* VTg = (bf16_t*)(ws + 80 * MB);   // V^T written directly by gemm_qkv
  bf16_t* Ctx = (bf16_t*)(ws + 96 * MB);
  if (ws_size < 112 * MB) return;

  cast_kernel<<<dim3(MROWS * DMODEL / (256 * 8)), 256, 0, stream>>>(x, Xb);
  transpose_cast<<<dim3(32, 32, 4), 256, 0, stream>>>(Wq, Wk, Wv, Wo, WqT, WkT, WvT, WoT);
  gemm_qkv<<<dim3(768), 512, 0, stream>>>(
      Xb, WqT, WkT, WvT, bq, bk, bv, Qg, Kg, VTg);
  attn_kernel<<<dim3(512), 256, 0, stream>>>(Qg, Kg, VTg, Ctx);
  gemm_out<<<dim3(DMODEL / 256, MROWS / 128), 512, 0, stream>>>(Ctx, WoT, bo, (float*)d_out);
}

// Round 12
// 216.757 us; speedup vs baseline: 1.1405x; 1.0174x over previous
//
#include <hip/hip_runtime.h>
#include <hip/hip_bf16.h>
#include <stdint.h>

#define S_LEN  2048
#define DMODEL 2048
#define NHEADS 16
#define DHEAD  128
#define NBATCH 2
#define MROWS  (NBATCH * S_LEN)   // 4096

typedef __bf16 bf16_t;
typedef __bf16 bf16x8 __attribute__((ext_vector_type(8)));
typedef float  f32x4  __attribute__((ext_vector_type(4)));
typedef float  f32x16 __attribute__((ext_vector_type(16)));

#define MFMA_BF16(A, B, C) __builtin_amdgcn_mfma_f32_16x16x32_bf16((A), (B), (C), 0, 0, 0)
#define MFMA32(A, B, C)    __builtin_amdgcn_mfma_f32_32x32x16_bf16((A), (B), (C), 0, 0, 0)

__device__ __forceinline__ void gload_lds16(const void* g, void* l) {
  __builtin_amdgcn_global_load_lds(
      (__attribute__((address_space(1))) uint32_t*)(uintptr_t)g,
      (__attribute__((address_space(3))) uint32_t*)l,
      16, 0, 0);
}

__device__ __forceinline__ unsigned pk2(float lo, float hi) {
  const unsigned short a = __builtin_bit_cast(unsigned short, (bf16_t)lo);
  const unsigned short b = __builtin_bit_cast(unsigned short, (bf16_t)hi);
  return (unsigned)a | ((unsigned)b << 16);
}

// ---------------- prep: x cast (blocks 4096..8191) + 4x W transpose (0..4095)
__global__ __launch_bounds__(256) void prep_kernel(
    const float* __restrict__ X, bf16_t* __restrict__ Xb,
    const float* __restrict__ W0, const float* __restrict__ W1,
    const float* __restrict__ W2, const float* __restrict__ W3,
    bf16_t* __restrict__ T0, bf16_t* __restrict__ T1,
    bf16_t* __restrict__ T2, bf16_t* __restrict__ T3) {
  const int bid = blockIdx.x;
  if (bid >= 4096) {
    const int i = (bid - 4096) * 256 + threadIdx.x;
    const f32x4 a = ((const f32x4*)X)[2 * i];
    const f32x4 b = ((const f32x4*)X)[2 * i + 1];
    bf16x8 o;
#pragma unroll
    for (int j = 0; j < 4; ++j) { o[j] = (bf16_t)a[j]; o[j + 4] = (bf16_t)b[j]; }
    ((bf16x8*)Xb)[i] = o;
    return;
  }
  const int wz  = bid >> 10;
  const int rem = bid & 1023;
  const float* W; bf16_t* T;
  switch (wz) {
    case 0:  W = W0; T = T0; break;
    case 1:  W = W1; T = T1; break;
    case 2:  W = W2; T = T2; break;
    default: W = W3; T = T3; break;
  }
  __shared__ float tile[64][65];
  const int r0 = (rem >> 5) * 64;
  const int c0 = (rem & 31) * 64;
  const int tx = threadIdx.x & 63;
  const int ty = threadIdx.x >> 6;
#pragma unroll
  for (int i = 0; i < 16; ++i) {
    const int r = ty + i * 4;
    tile[r][tx] = W[(size_t)(r0 + r) * DMODEL + c0 + tx];
  }
  __syncthreads();
#pragma unroll
  for (int i = 0; i < 16; ++i) {
    const int r = ty + i * 4;
    T[(size_t)(c0 + r) * DMODEL + r0 + tx] = (bf16_t)tile[tx][r];
  }
}

// ------------------------------------------- R4 GEMM body: BM=128 BN=256 BK=64
// Proven main loop (0 conflicts). setprio removed per m190 (lockstep GEMM: -1.5%).
// Epilogue: mode 0 bf16 scatter [B,H,S,D]; mode 1 f32 [M][2048]; mode 2 VT.
__device__ __forceinline__ void gemm8_body(const bf16_t* __restrict__ A,
                                           const bf16_t* __restrict__ Bt,
                                           const float* __restrict__ bias,
                                           void* __restrict__ out,
                                           int m0, int n0, int mode) {
  __shared__ __align__(16) char lds8[2 * 49152];   // 96 KB
  const int tid  = threadIdx.x;
  const int lane = tid & 63;
  const int w    = tid >> 6;
  const int g    = lane >> 4;
  const int l16  = lane & 15;
  const int wm   = w >> 2;       // 0..1
  const int wn   = w & 3;        // 0..3

  f32x4 acc[4][4];
#pragma unroll
  for (int i = 0; i < 4; ++i)
#pragma unroll
    for (int j = 0; j < 4; ++j) acc[i][j] = (f32x4){0.f, 0.f, 0.f, 0.f};

  const int st_r0 = tid >> 3;
  const int st_ch = tid & 7;

  auto stage = [&](int tile, int r) {
    if (tile >= DMODEL / 64) return;
    const int kt = tile << 6;
    char* db = lds8 + (tile & 1) * 49152 + r * 16384 + w * 1024;
    const bf16_t* sb = (r == 0) ? (A + (size_t)m0 * DMODEL + kt)
                                : (Bt + (size_t)(n0 + ((r - 1) << 7)) * DMODEL + kt);
#pragma unroll
    for (int jj = 0; jj < 2; ++jj) {
      const int row = jj * 64 + st_r0;
      gload_lds16(sb + (size_t)row * DMODEL + ((st_ch ^ (row & 7)) << 3),
                  db + jj * 8192);
    }
  };

  stage(0, 0); stage(0, 1); stage(0, 2); stage(1, 0);
  asm volatile("s_waitcnt vmcnt(2)" ::: "memory");
  __builtin_amdgcn_s_barrier();

#pragma unroll 2
  for (int t = 0; t < DMODEL / 64; ++t) {
    const char* cb = lds8 + (t & 1) * 49152;
    bf16x8 af[4][2], b0[2][2], b1[2][2];
#pragma unroll
    for (int i = 0; i < 4; ++i) {
      const int row = wm * 64 + i * 16 + l16;
      const char* rp = cb + row * 128;
#pragma unroll
      for (int ks = 0; ks < 2; ++ks)
        af[i][ks] = *(const bf16x8*)(rp + ((((ks << 2) | g) ^ (row & 7)) << 4));
    }
#pragma unroll
    for (int j = 0; j < 2; ++j) {
      const int row = (wn & 1) * 64 + j * 16 + l16;
      const char* rp = cb + 16384 + (wn >> 1) * 16384 + row * 128;
#pragma unroll
      for (int ks = 0; ks < 2; ++ks)
        b0[j][ks] = *(const bf16x8*)(rp + ((((ks << 2) | g) ^ (row & 7)) << 4));
    }
    stage(t + 1, 1); stage(t + 1, 2);
    __builtin_amdgcn_s_barrier();
    asm volatile("s_waitcnt lgkmcnt(0)" ::: "memory");
#pragma unroll
    for (int i = 0; i < 4; ++i)
#pragma unroll
      for (int j = 0; j < 2; ++j) {
        acc[i][j] = MFMA_BF16(af[i][0], b0[j][0], acc[i][j]);
        acc[i][j] = MFMA_BF16(af[i][1], b0[j][1], acc[i][j]);
      }
    __builtin_amdgcn_s_barrier();
#pragma unroll
    for (int j = 0; j < 2; ++j) {
      const int row = (wn & 1) * 64 + (j + 2) * 16 + l16;
      const char* rp = cb + 16384 + (wn >> 1) * 16384 + row * 128;
#pragma unroll
      for (int ks = 0; ks < 2; ++ks)
        b1[j][ks] = *(const bf16x8*)(rp + ((((ks << 2) | g) ^ (row & 7)) << 4));
    }
    stage(t + 2, 0);
    __builtin_amdgcn_s_barrier();
    asm volatile("s_waitcnt lgkmcnt(0)" ::: "memory");
#pragma unroll
    for (int i = 0; i < 4; ++i)
#pragma unroll
      for (int j = 0; j < 2; ++j) {
        acc[i][j + 2] = MFMA_BF16(af[i][0], b1[j][0], acc[i][j + 2]);
        acc[i][j + 2] = MFMA_BF16(af[i][1], b1[j][1], acc[i][j + 2]);
      }
    if (t < DMODEL / 64 - 2) asm volatile("s_waitcnt vmcnt(2)" ::: "memory");
    else                     asm volatile("s_waitcnt vmcnt(0)" ::: "memory");
    __builtin_amdgcn_s_barrier();
  }

  if (mode == 2) {
    // V: transpose through LDS, write VT[bh][d][s] coalesced.
    bf16_t* tr = (bf16_t*)lds8;      // [n 256][m 128] stride 136 elems
#pragma unroll
    for (int i = 0; i < 4; ++i) {
#pragma unroll
      for (int j = 0; j < 4; ++j) {
        const int nl = wn * 64 + j * 16 + l16;
        const int ml = wm * 64 + i * 16 + g * 4;
        const float bb = bias[n0 + nl];
        union { unsigned short u[4]; uint64_t v; } pk;
#pragma unroll
        for (int r = 0; r < 4; ++r)
          pk.u[r] = __builtin_bit_cast(unsigned short, (bf16_t)(acc[i][j][r] + bb));
        *(uint64_t*)&tr[nl * 136 + ml] = pk.v;
      }
    }
    __syncthreads();
    const int b = m0 >> 11;
    const int s0 = m0 & (S_LEN - 1);
#pragma unroll
    for (int it = 0; it < 8; ++it) {
      const int c   = it * 512 + tid;   // 0..4095 exactly
      const int nl  = c >> 4;
      const int ml8 = c & 15;
      const bf16x8 v = *(const bf16x8*)&tr[nl * 136 + ml8 * 8];
      const int n  = n0 + nl;
      const int h  = n >> 7, dd = n & (DHEAD - 1);
      *(bf16x8*)((bf16_t*)out +
                 ((size_t)(b * NHEADS + h) * DHEAD + dd) * S_LEN + s0 + ml8 * 8) = v;
    }
    return;
  }

#pragma unroll
  for (int i = 0; i < 4; ++i) {
#pragma unroll
    for (int j = 0; j < 4; ++j) {
      const int n    = n0 + wn * 64 + j * 16 + l16;
      const float bb = bias[n];
#pragma unroll
      for (int r = 0; r < 4; ++r) {
        const int m   = m0 + wm * 64 + i * 16 + g * 4 + r;
        const float v = acc[i][j][r] + bb;
        if (mode == 0) {
          const int b = m >> 11, s = m & (S_LEN - 1);
          const int h = n >> 7,  d = n & (DHEAD - 1);
          ((bf16_t*)out)[((size_t)(b * NHEADS + h) * S_LEN + s) * DHEAD + d] = (bf16_t)v;
        } else {
          ((float*)out)[(size_t)m * DMODEL + n] = v;
        }
      }
    }
  }
}

// QKV: 1-D grid 768, bijective XCD swizzle (768 = 8 XCD x 96).
__global__ __launch_bounds__(512, 2) void gemm_qkv(
    const bf16_t* __restrict__ Xb,
    const bf16_t* __restrict__ WqT, const bf16_t* __restrict__ WkT,
    const bf16_t* __restrict__ WvT,
    const float* __restrict__ bq, const float* __restrict__ bk,
    const float* __restrict__ bv,
    bf16_t* __restrict__ Qg, bf16_t* __restrict__ Kg, bf16_t* __restrict__ VTg) {
  const int bid = blockIdx.x;
  const int wg  = (bid & 7) * 96 + (bid >> 3);
  const int x   = wg & 7;
  const int y   = (wg >> 3) & 31;
  const int z0  = wg >> 8;
  const bf16_t* Bt  = (z0 == 0) ? WqT : (z0 == 1) ? WkT : WvT;
  const float* bias = (z0 == 0) ? bq  : (z0 == 1) ? bk  : bv;
  void* out         = (z0 == 0) ? (void*)Qg : (z0 == 1) ? (void*)Kg : (void*)VTg;
  gemm8_body(Xb, Bt, bias, out, y * 128, x * 256, (z0 == 2) ? 2 : 0);
}

__global__ __launch_bounds__(512, 2) void gemm_out(
    const bf16_t* __restrict__ Ctx, const bf16_t* __restrict__ WoT,
    const float* __restrict__ bo, float* __restrict__ out) {
  gemm8_body(Ctx, WoT, bo, out, blockIdx.y * 128, blockIdx.x * 256, 1);
}

// --------------------------------------------------------------- flash attention
#define KTILE_B 16384
#define VTILE_B 16384
#define ABUF_B  (KTILE_B + VTILE_B)   // 32 KB per buffer

__global__ __launch_bounds__(256, 2) void attn_kernel(
    const bf16_t* __restrict__ Qg, const bf16_t* __restrict__ Kg,
    const bf16_t* __restrict__ VTg, bf16_t* __restrict__ ctx) {
  __shared__ __align__(16) char ldsbuf[2][ABUF_B];
  __shared__ float lbuf[4][32];

  const int tid  = threadIdx.x;
  const int lane = tid & 63;
  const int w    = tid >> 6;
  const int l31  = lane & 31;
  const int hi   = lane >> 5;

  const int id   = blockIdx.x;                  // 512 blocks
  const int bh   = id & 31;
  const int jraw = id >> 5;
  const int j    = (jraw < 8) ? jraw : 23 - jraw;
  const int q0   = j * 128;
  const int qw   = q0 + w * 32;
  const int tq   = (qw + 31) >> 6;
  const int NT   = (q0 + 128) >> 6;

  const size_t bho = (size_t)bh * S_LEN * DHEAD;
  const bf16_t* Qb  = Qg + bho;
  const bf16_t* Kb  = Kg + bho;
  const bf16_t* VTb = VTg + bho;                // [128][2048]

  auto stageT = [&](int t) {
    const int kt = t << 6;
    char* dst = ldsbuf[t & 1];
#pragma unroll
    for (int i = 0; i < 4; ++i) {                 // K: 64 rows x 256B
      const int c   = i * 256 + tid;
      const int row = c >> 4, ch = c & 15;
      gload_lds16(Kb + (size_t)(kt + row) * DHEAD + ((ch ^ (row & 7)) << 3),
                  dst + (i * 256 + (tid & ~63)) * 16);
    }
#pragma unroll
    for (int i = 0; i < 4; ++i) {                 // VT: 128 rows x 128B
      const int c   = i * 256 + tid;
      const int row = c >> 3, ch = c & 7;
      gload_lds16(VTb + (size_t)row * S_LEN + kt + ((ch ^ (row & 7)) << 3),
                  dst + KTILE_B + (i * 256 + (tid & ~63)) * 16);
    }
  };

  bf16x8 qreg[8];
#pragma unroll
  for (int s = 0; s < 8; ++s)
    qreg[s] = *(const bf16x8*)(Qb + (size_t)(qw + l31) * DHEAD + s * 16 + hi * 8);

  f32x16 oacc[4];
#pragma unroll
  for (int d0 = 0; d0 < 4; ++d0)
#pragma unroll
    for (int e = 0; e < 16; ++e) oacc[d0][e] = 0.f;

  float m = -1e30f, lsum = 0.f;
  const float sc2 = 0.12751751135f;             // log2(e)/sqrt(128)

  stageT(0);
  asm volatile("s_waitcnt vmcnt(0)" ::: "memory");
  __syncthreads();

  for (int t = 0; t < NT; ++t) {
    const char* bK = ldsbuf[t & 1];
    const char* bV = bK + KTILE_B;
    if (t + 1 < NT) stageT(t + 1);

    if (t <= tq) {
      const int kt = t << 6;
      f32x16 stt[2];
#pragma unroll
      for (int kh = 0; kh < 2; ++kh)
#pragma unroll
        for (int e = 0; e < 16; ++e) stt[kh][e] = 0.f;
#pragma unroll
      for (int kh = 0; kh < 2; ++kh) {
        const int row = kh * 32 + l31;
        const char* rb = bK + row * 256;
        const int swz = (row & 7) << 4;
#pragma unroll
        for (int s = 0; s < 8; ++s) {
          const bf16x8 kf = *(const bf16x8*)(rb + ((((s << 1) | hi) << 4) ^ swz));
          stt[kh] = MFMA32(kf, qreg[s], stt[kh]);
        }
      }
      if (t == tq) {
        const int qg = qw + l31;
#pragma unroll
        for (int kh = 0; kh < 2; ++kh)
#pragma unroll
          for (int r = 0; r < 16; ++r) {
            const int kv = kt + kh * 32 + (r & 3) + 8 * (r >> 2) + 4 * hi;
            stt[kh][r] = (kv > qg) ? -1e30f : stt[kh][r];
          }
      }
      // row max: max3-fusable tree (fmaxf(pm, fmaxf(a,b)))
      float pm = fmaxf(stt[0][0], stt[1][0]);
#pragma unroll
      for (int r = 1; r < 16; ++r)
        pm = fmaxf(pm, fmaxf(stt[0][r], stt[1][r]));
      pm = fmaxf(pm, __shfl_xor(pm, 32));
      const float pmax = pm * sc2;
      if (!__all(pmax <= m + 8.f)) {
        const float mn   = fmaxf(m, pmax);
        const float corr = __builtin_amdgcn_exp2f(m - mn);
        m = mn;
        lsum *= corr;
        if (!hi) lbuf[w][l31] = corr;
#pragma unroll
        for (int r = 0; r < 16; ++r) {
          const float cr = lbuf[w][(r & 3) + 8 * (r >> 2) + 4 * hi];
#pragma unroll
          for (int d0 = 0; d0 < 4; ++d0) oacc[d0][r] *= cr;
        }
      }
      float rs = 0.f;
#pragma unroll
      for (int kh = 0; kh < 2; ++kh)
#pragma unroll
        for (int r = 0; r < 16; ++r) {
          const float p = __builtin_amdgcn_exp2f(__builtin_fmaf(stt[kh][r], sc2, -m));
          stt[kh][r] = p;
          rs += p;
        }
      rs += __shfl_xor(rs, 32);
      lsum += rs;
      unsigned pw_[2][8];
#pragma unroll
      for (int kh = 0; kh < 2; ++kh)
#pragma unroll
        for (int jj = 0; jj < 8; ++jj)
          pw_[kh][jj] = pk2(stt[kh][2 * jj], stt[kh][2 * jj + 1]);
      bf16x8 pa[4];
#pragma unroll
      for (int kh = 0; kh < 2; ++kh)
#pragma unroll
        for (int c2 = 0; c2 < 2; ++c2) {
          const unsigned o0 = pw_[kh][4 * c2 + 0], o1 = pw_[kh][4 * c2 + 1];
          const unsigned o2 = pw_[kh][4 * c2 + 2], o3 = pw_[kh][4 * c2 + 3];
          const unsigned p0 = (unsigned)__shfl_xor((int)o0, 32);
          const unsigned p1 = (unsigned)__shfl_xor((int)o1, 32);
          const unsigned p2 = (unsigned)__shfl_xor((int)o2, 32);
          const unsigned p3 = (unsigned)__shfl_xor((int)o3, 32);
          union { unsigned u[4]; bf16x8 v; } uu;
          uu.u[0] = hi ? p2 : o0;
          uu.u[1] = hi ? p3 : o1;
          uu.u[2] = hi ? o2 : p0;
          uu.u[3] = hi ? o3 : p1;
          pa[2 * kh + c2] = uu.v;
        }
#pragma unroll
      for (int d0 = 0; d0 < 4; ++d0) {
        const int row = d0 * 32 + l31;
        const char* rb = bV + row * 128;
        const int swz = (row & 7) << 4;
#pragma unroll
        for (int ks = 0; ks < 4; ++ks) {
          const bf16x8 vb = *(const bf16x8*)(rb + ((((ks << 1) | hi) << 4) ^ swz));
          oacc[d0] = MFMA32(pa[ks], vb, oacc[d0]);
        }
      }
    }
    asm volatile("s_waitcnt vmcnt(0)" ::: "memory");
    __syncthreads();
  }

  if (!hi) lbuf[w][l31] = 1.0f / lsum;
  const int b = bh >> 4, h = bh & 15;
#pragma unroll
  for (int r = 0; r < 16; ++r) {
    const int cro = (r & 3) + 8 * (r >> 2) + 4 * hi;
    const float li = lbuf[w][cro];
    const size_t base = ((size_t)(b * S_LEN + qw + cro)) * DMODEL + h * DHEAD;
#pragma unroll
    for (int d0 = 0; d0 < 4; ++d0)
      ctx[base + d0 * 32 + l31] = (bf16_t)(oacc[d0][r] * li);
  }
}

// ------------------------------------------------------------------------- launch
extern "C" void kernel_launch(void* const* d_in, const int* in_sizes, int n_in,
                              void* d_out, int out_size, void* d_ws, size_t ws_size,
                              hipStream_t stream) {
  const float* x  = (const float*)d_in[0];
  const float* Wq = (const float*)d_in[1];
  const float* bq = (const float*)d_in[2];
  const float* Wk = (const float*)d_in[3];
  const float* bk = (const float*)d_in[4];
  const float* Wv = (const float*)d_in[5];
  const float* bv = (const float*)d_in[6];
  const float* Wo = (const float*)d_in[7];
  const float* bo = (const float*)d_in[8];

  char* ws = (char*)d_ws;
  const size_t MB = 1ull << 20;
  bf16_t* Xb  = (bf16_t*)(ws + 0);
  bf16_t* WqT = (bf16_t*)(ws + 16 * MB);
  bf16_t* WkT = (bf16_t*)(ws + 24 * MB);
  bf16_t* WvT = (bf16_t*)(ws + 32 * MB);
  bf16_t* WoT = (bf16_t*)(ws + 40 * MB);
  bf16_t* Qg  = (bf16_t*)(ws + 48 * MB);
  bf16_t* Kg  = (bf16_t*)(ws + 64 * MB);
  bf16_t* VTg = (bf16_t*)(ws + 80 * MB);   // V^T written directly by gemm_qkv
  bf16_t* Ctx = (bf16_t*)(ws + 96 * MB);
  if (ws_size < 112 * MB) return;

  prep_kernel<<<dim3(8192), 256, 0, stream>>>(x, Xb, Wq, Wk, Wv, Wo,
                                              WqT, WkT, WvT, WoT);
  gemm_qkv<<<dim3(768), 512, 0, stream>>>(
      Xb, WqT, WkT, WvT, bq, bk, bv, Qg, Kg, VTg);
  attn_kernel<<<dim3(512), 256, 0, stream>>>(Qg, Kg, VTg, Ctx);
  gemm_out<<<dim3(DMODEL / 256, MROWS / 128), 512, 0, stream>>>(Ctx, WoT, bo, (float*)d_out);
}

// Round 13
// 215.654 us; speedup vs baseline: 1.1464x; 1.0051x over previous
//
#include <hip/hip_runtime.h>
#include <hip/hip_bf16.h>
#include <stdint.h>

#define S_LEN  2048
#define DMODEL 2048
#define NHEADS 16
#define DHEAD  128
#define NBATCH 2
#define MROWS  (NBATCH * S_LEN)   // 4096

typedef __bf16 bf16_t;
typedef __bf16 bf16x8 __attribute__((ext_vector_type(8)));
typedef float  f32x4  __attribute__((ext_vector_type(4)));
typedef float  f32x16 __attribute__((ext_vector_type(16)));

#define MFMA_BF16(A, B, C) __builtin_amdgcn_mfma_f32_16x16x32_bf16((A), (B), (C), 0, 0, 0)
#define MFMA32(A, B, C)    __builtin_amdgcn_mfma_f32_32x32x16_bf16((A), (B), (C), 0, 0, 0)

__device__ __forceinline__ void gload_lds16(const void* g, void* l) {
  __builtin_amdgcn_global_load_lds(
      (__attribute__((address_space(1))) uint32_t*)(uintptr_t)g,
      (__attribute__((address_space(3))) uint32_t*)l,
      16, 0, 0);
}

__device__ __forceinline__ unsigned pk2(float lo, float hi) {
  const unsigned short a = __builtin_bit_cast(unsigned short, (bf16_t)lo);
  const unsigned short b = __builtin_bit_cast(unsigned short, (bf16_t)hi);
  return (unsigned)a | ((unsigned)b << 16);
}

// ---------------- prep: x cast (blocks 4096..8191) + 4x W transpose (0..4095)
__global__ __launch_bounds__(256) void prep_kernel(
    const float* __restrict__ X, bf16_t* __restrict__ Xb,
    const float* __restrict__ W0, const float* __restrict__ W1,
    const float* __restrict__ W2, const float* __restrict__ W3,
    bf16_t* __restrict__ T0, bf16_t* __restrict__ T1,
    bf16_t* __restrict__ T2, bf16_t* __restrict__ T3) {
  const int bid = blockIdx.x;
  if (bid >= 4096) {
    const int i = (bid - 4096) * 256 + threadIdx.x;
    const f32x4 a = ((const f32x4*)X)[2 * i];
    const f32x4 b = ((const f32x4*)X)[2 * i + 1];
    bf16x8 o;
#pragma unroll
    for (int j = 0; j < 4; ++j) { o[j] = (bf16_t)a[j]; o[j + 4] = (bf16_t)b[j]; }
    ((bf16x8*)Xb)[i] = o;
    return;
  }
  const int wz  = bid >> 10;
  const int rem = bid & 1023;
  const float* W; bf16_t* T;
  switch (wz) {
    case 0:  W = W0; T = T0; break;
    case 1:  W = W1; T = T1; break;
    case 2:  W = W2; T = T2; break;
    default: W = W3; T = T3; break;
  }
  __shared__ float tile[64][65];
  const int r0 = (rem >> 5) * 64;
  const int c0 = (rem & 31) * 64;
  const int tx = threadIdx.x & 63;
  const int ty = threadIdx.x >> 6;
#pragma unroll
  for (int i = 0; i < 16; ++i) {
    const int r = ty + i * 4;
    tile[r][tx] = W[(size_t)(r0 + r) * DMODEL + c0 + tx];
  }
  __syncthreads();
#pragma unroll
  for (int i = 0; i < 16; ++i) {
    const int r = ty + i * 4;
    T[(size_t)(c0 + r) * DMODEL + r0 + tx] = (bf16_t)tile[tx][r];
  }
}

// ------------------------------------------- R4 GEMM body: BM=128 BN=256 BK=64
// 2 barriers/K-tile (pre-MFMA barriers removed — no LDS hazard crosses them;
// B1 = end-of-phase-0 fences stage(t+2,A) overwrite, B2 = post-vmcnt visibility).
// setprio removed per m190. Epilogue: mode 0 bf16 [B,H,S,D]; 1 f32; 2 VT.
__device__ __forceinline__ void gemm8_body(const bf16_t* __restrict__ A,
                                           const bf16_t* __restrict__ Bt,
                                           const float* __restrict__ bias,
                                           void* __restrict__ out,
                                           int m0, int n0, int mode) {
  __shared__ __align__(16) char lds8[2 * 49152];   // 96 KB
  const int tid  = threadIdx.x;
  const int lane = tid & 63;
  const int w    = tid >> 6;
  const int g    = lane >> 4;
  const int l16  = lane & 15;
  const int wm   = w >> 2;       // 0..1
  const int wn   = w & 3;        // 0..3

  f32x4 acc[4][4];
#pragma unroll
  for (int i = 0; i < 4; ++i)
#pragma unroll
    for (int j = 0; j < 4; ++j) acc[i][j] = (f32x4){0.f, 0.f, 0.f, 0.f};

  const int st_r0 = tid >> 3;
  const int st_ch = tid & 7;

  auto stage = [&](int tile, int r) {
    if (tile >= DMODEL / 64) return;
    const int kt = tile << 6;
    char* db = lds8 + (tile & 1) * 49152 + r * 16384 + w * 1024;
    const bf16_t* sb = (r == 0) ? (A + (size_t)m0 * DMODEL + kt)
                                : (Bt + (size_t)(n0 + ((r - 1) << 7)) * DMODEL + kt);
#pragma unroll
    for (int jj = 0; jj < 2; ++jj) {
      const int row = jj * 64 + st_r0;
      gload_lds16(sb + (size_t)row * DMODEL + ((st_ch ^ (row & 7)) << 3),
                  db + jj * 8192);
    }
  };

  stage(0, 0); stage(0, 1); stage(0, 2); stage(1, 0);
  asm volatile("s_waitcnt vmcnt(2)" ::: "memory");
  __builtin_amdgcn_s_barrier();

#pragma unroll 2
  for (int t = 0; t < DMODEL / 64; ++t) {
    const char* cb = lds8 + (t & 1) * 49152;
    bf16x8 af[4][2], b0[2][2], b1[2][2];
    // ---- phase 0: read A frags + B(nj 0-1); stage t+1 B halves; MFMA
#pragma unroll
    for (int i = 0; i < 4; ++i) {
      const int row = wm * 64 + i * 16 + l16;
      const char* rp = cb + row * 128;
#pragma unroll
      for (int ks = 0; ks < 2; ++ks)
        af[i][ks] = *(const bf16x8*)(rp + ((((ks << 2) | g) ^ (row & 7)) << 4));
    }
#pragma unroll
    for (int j = 0; j < 2; ++j) {
      const int row = (wn & 1) * 64 + j * 16 + l16;
      const char* rp = cb + 16384 + (wn >> 1) * 16384 + row * 128;
#pragma unroll
      for (int ks = 0; ks < 2; ++ks)
        b0[j][ks] = *(const bf16x8*)(rp + ((((ks << 2) | g) ^ (row & 7)) << 4));
    }
    stage(t + 1, 1); stage(t + 1, 2);
    asm volatile("s_waitcnt lgkmcnt(0)" ::: "memory");
#pragma unroll
    for (int i = 0; i < 4; ++i)
#pragma unroll
      for (int j = 0; j < 2; ++j) {
        acc[i][j] = MFMA_BF16(af[i][0], b0[j][0], acc[i][j]);
        acc[i][j] = MFMA_BF16(af[i][1], b0[j][1], acc[i][j]);
      }
    __builtin_amdgcn_s_barrier();   // B1: all waves' phase-0 reads complete
    // ---- phase 1: read B(nj 2-3); stage t+2 A (A-region now dead); MFMA
#pragma unroll
    for (int j = 0; j < 2; ++j) {
      const int row = (wn & 1) * 64 + (j + 2) * 16 + l16;
      const char* rp = cb + 16384 + (wn >> 1) * 16384 + row * 128;
#pragma unroll
      for (int ks = 0; ks < 2; ++ks)
        b1[j][ks] = *(const bf16x8*)(rp + ((((ks << 2) | g) ^ (row & 7)) << 4));
    }
    stage(t + 2, 0);
    asm volatile("s_waitcnt lgkmcnt(0)" ::: "memory");
#pragma unroll
    for (int i = 0; i < 4; ++i)
#pragma unroll
      for (int j = 0; j < 2; ++j) {
        acc[i][j + 2] = MFMA_BF16(af[i][0], b1[j][0], acc[i][j + 2]);
        acc[i][j + 2] = MFMA_BF16(af[i][1], b1[j][1], acc[i][j + 2]);
      }
    if (t < DMODEL / 64 - 2) asm volatile("s_waitcnt vmcnt(2)" ::: "memory");
    else                     asm volatile("s_waitcnt vmcnt(0)" ::: "memory");
    __builtin_amdgcn_s_barrier();   // B2: staged tile visible to all waves
  }

  if (mode == 2) {
    // V: transpose through LDS, write VT[bh][d][s] coalesced.
    bf16_t* tr = (bf16_t*)lds8;      // [n 256][m 128] stride 136 elems
#pragma unroll
    for (int i = 0; i < 4; ++i) {
#pragma unroll
      for (int j = 0; j < 4; ++j) {
        const int nl = wn * 64 + j * 16 + l16;
        const int ml = wm * 64 + i * 16 + g * 4;
        const float bb = bias[n0 + nl];
        union { unsigned short u[4]; uint64_t v; } pk;
#pragma unroll
        for (int r = 0; r < 4; ++r)
          pk.u[r] = __builtin_bit_cast(unsigned short, (bf16_t)(acc[i][j][r] + bb));
        *(uint64_t*)&tr[nl * 136 + ml] = pk.v;
      }
    }
    __syncthreads();
    const int b = m0 >> 11;
    const int s0 = m0 & (S_LEN - 1);
#pragma unroll
    for (int it = 0; it < 8; ++it) {
      const int c   = it * 512 + tid;   // 0..4095 exactly
      const int nl  = c >> 4;
      const int ml8 = c & 15;
      const bf16x8 v = *(const bf16x8*)&tr[nl * 136 + ml8 * 8];
      const int n  = n0 + nl;
      const int h  = n >> 7, dd = n & (DHEAD - 1);
      *(bf16x8*)((bf16_t*)out +
                 ((size_t)(b * NHEADS + h) * DHEAD + dd) * S_LEN + s0 + ml8 * 8) = v;
    }
    return;
  }

#pragma unroll
  for (int i = 0; i < 4; ++i) {
#pragma unroll
    for (int j = 0; j < 4; ++j) {
      const int n    = n0 + wn * 64 + j * 16 + l16;
      const float bb = bias[n];
#pragma unroll
      for (int r = 0; r < 4; ++r) {
        const int m   = m0 + wm * 64 + i * 16 + g * 4 + r;
        const float v = acc[i][j][r] + bb;
        if (mode == 0) {
          const int b = m >> 11, s = m & (S_LEN - 1);
          const int h = n >> 7,  d = n & (DHEAD - 1);
          ((bf16_t*)out)[((size_t)(b * NHEADS + h) * S_LEN + s) * DHEAD + d] = (bf16_t)v;
        } else {
          ((float*)out)[(size_t)m * DMODEL + n] = v;
        }
      }
    }
  }
}

// QKV: 1-D grid 768, bijective XCD swizzle (768 = 8 XCD x 96).
__global__ __launch_bounds__(512, 2) void gemm_qkv(
    const bf16_t* __restrict__ Xb,
    const bf16_t* __restrict__ WqT, const bf16_t* __restrict__ WkT,
    const bf16_t* __restrict__ WvT,
    const float* __restrict__ bq, const float* __restrict__ bk,
    const float* __restrict__ bv,
    bf16_t* __restrict__ Qg, bf16_t* __restrict__ Kg, bf16_t* __restrict__ VTg) {
  const int bid = blockIdx.x;
  const int wg  = (bid & 7) * 96 + (bid >> 3);
  const int x   = wg & 7;
  const int y   = (wg >> 3) & 31;
  const int z0  = wg >> 8;
  const bf16_t* Bt  = (z0 == 0) ? WqT : (z0 == 1) ? WkT : WvT;
  const float* bias = (z0 == 0) ? bq  : (z0 == 1) ? bk  : bv;
  void* out         = (z0 == 0) ? (void*)Qg : (z0 == 1) ? (void*)Kg : (void*)VTg;
  gemm8_body(Xb, Bt, bias, out, y * 128, x * 256, (z0 == 2) ? 2 : 0);
}

__global__ __launch_bounds__(512, 2) void gemm_out(
    const bf16_t* __restrict__ Ctx, const bf16_t* __restrict__ WoT,
    const float* __restrict__ bo, float* __restrict__ out) {
  gemm8_body(Ctx, WoT, bo, out, blockIdx.y * 128, blockIdx.x * 256, 1);
}

// --------------------------------------------------------------- flash attention
#define KTILE_B 16384
#define VTILE_B 16384
#define ABUF_B  (KTILE_B + VTILE_B)   // 32 KB per buffer

__global__ __launch_bounds__(256, 2) void attn_kernel(
    const bf16_t* __restrict__ Qg, const bf16_t* __restrict__ Kg,
    const bf16_t* __restrict__ VTg, bf16_t* __restrict__ ctx) {
  __shared__ __align__(16) char ldsbuf[2][ABUF_B];
  __shared__ float lbuf[4][32];

  const int tid  = threadIdx.x;
  const int lane = tid & 63;
  const int w    = tid >> 6;
  const int l31  = lane & 31;
  const int hi   = lane >> 5;

  const int id   = blockIdx.x;                  // 512 blocks
  const int bh   = id & 31;
  const int jraw = id >> 5;
  const int j    = (jraw < 8) ? jraw : 23 - jraw;
  const int q0   = j * 128;
  const int qw   = q0 + w * 32;
  const int tq   = (qw + 31) >> 6;
  const int NT   = (q0 + 128) >> 6;

  const size_t bho = (size_t)bh * S_LEN * DHEAD;
  const bf16_t* Qb  = Qg + bho;
  const bf16_t* Kb  = Kg + bho;
  const bf16_t* VTb = VTg + bho;                // [128][2048]

  auto stageT = [&](int t) {
    const int kt = t << 6;
    char* dst = ldsbuf[t & 1];
#pragma unroll
    for (int i = 0; i < 4; ++i) {                 // K: 64 rows x 256B
      const int c   = i * 256 + tid;
      const int row = c >> 4, ch = c & 15;
      gload_lds16(Kb + (size_t)(kt + row) * DHEAD + ((ch ^ (row & 7)) << 3),
                  dst + (i * 256 + (tid & ~63)) * 16);
    }
#pragma unroll
    for (int i = 0; i < 4; ++i) {                 // VT: 128 rows x 128B
      const int c   = i * 256 + tid;
      const int row = c >> 3, ch = c & 7;
      gload_lds16(VTb + (size_t)row * S_LEN + kt + ((ch ^ (row & 7)) << 3),
                  dst + KTILE_B + (i * 256 + (tid & ~63)) * 16);
    }
  };

  bf16x8 qreg[8];
#pragma unroll
  for (int s = 0; s < 8; ++s)
    qreg[s] = *(const bf16x8*)(Qb + (size_t)(qw + l31) * DHEAD + s * 16 + hi * 8);

  f32x16 oacc[4];
#pragma unroll
  for (int d0 = 0; d0 < 4; ++d0)
#pragma unroll
    for (int e = 0; e < 16; ++e) oacc[d0][e] = 0.f;

  float m = -1e30f, lsum = 0.f;
  const float sc2 = 0.12751751135f;             // log2(e)/sqrt(128)

  stageT(0);
  asm volatile("s_waitcnt vmcnt(0)" ::: "memory");
  __syncthreads();

  for (int t = 0; t < NT; ++t) {
    const char* bK = ldsbuf[t & 1];
    const char* bV = bK + KTILE_B;
    if (t + 1 < NT) stageT(t + 1);

    if (t <= tq) {
      const int kt = t << 6;
      f32x16 stt[2];
#pragma unroll
      for (int kh = 0; kh < 2; ++kh)
#pragma unroll
        for (int e = 0; e < 16; ++e) stt[kh][e] = 0.f;
#pragma unroll
      for (int kh = 0; kh < 2; ++kh) {
        const int row = kh * 32 + l31;
        const char* rb = bK + row * 256;
        const int swz = (row & 7) << 4;
#pragma unroll
        for (int s = 0; s < 8; ++s) {
          const bf16x8 kf = *(const bf16x8*)(rb + ((((s << 1) | hi) << 4) ^ swz));
          stt[kh] = MFMA32(kf, qreg[s], stt[kh]);
        }
      }
      if (t == tq) {
        const int qg = qw + l31;
#pragma unroll
        for (int kh = 0; kh < 2; ++kh)
#pragma unroll
          for (int r = 0; r < 16; ++r) {
            const int kv = kt + kh * 32 + (r & 3) + 8 * (r >> 2) + 4 * hi;
            stt[kh][r] = (kv > qg) ? -1e30f : stt[kh][r];
          }
      }
      float pm = fmaxf(stt[0][0], stt[1][0]);
#pragma unroll
      for (int r = 1; r < 16; ++r)
        pm = fmaxf(pm, fmaxf(stt[0][r], stt[1][r]));
      pm = fmaxf(pm, __shfl_xor(pm, 32));
      const float pmax = pm * sc2;
      if (!__all(pmax <= m + 8.f)) {
        const float mn   = fmaxf(m, pmax);
        const float corr = __builtin_amdgcn_exp2f(m - mn);
        m = mn;
        lsum *= corr;
        if (!hi) lbuf[w][l31] = corr;
#pragma unroll
        for (int r = 0; r < 16; ++r) {
          const float cr = lbuf[w][(r & 3) + 8 * (r >> 2) + 4 * hi];
#pragma unroll
          for (int d0 = 0; d0 < 4; ++d0) oacc[d0][r] *= cr;
        }
      }
      float rs = 0.f;
#pragma unroll
      for (int kh = 0; kh < 2; ++kh)
#pragma unroll
        for (int r = 0; r < 16; ++r) {
          const float p = __builtin_amdgcn_exp2f(__builtin_fmaf(stt[kh][r], sc2, -m));
          stt[kh][r] = p;
          rs += p;
        }
      rs += __shfl_xor(rs, 32);
      lsum += rs;
      unsigned pw_[2][8];
#pragma unroll
      for (int kh = 0; kh < 2; ++kh)
#pragma unroll
        for (int jj = 0; jj < 8; ++jj)
          pw_[kh][jj] = pk2(stt[kh][2 * jj], stt[kh][2 * jj + 1]);
      bf16x8 pa[4];
#pragma unroll
      for (int kh = 0; kh < 2; ++kh)
#pragma unroll
        for (int c2 = 0; c2 < 2; ++c2) {
          const unsigned o0 = pw_[kh][4 * c2 + 0], o1 = pw_[kh][4 * c2 + 1];
          const unsigned o2 = pw_[kh][4 * c2 + 2], o3 = pw_[kh][4 * c2 + 3];
          const unsigned p0 = (unsigned)__shfl_xor((int)o0, 32);
          const unsigned p1 = (unsigned)__shfl_xor((int)o1, 32);
          const unsigned p2 = (unsigned)__shfl_xor((int)o2, 32);
          const unsigned p3 = (unsigned)__shfl_xor((int)o3, 32);
          union { unsigned u[4]; bf16x8 v; } uu;
          uu.u[0] = hi ? p2 : o0;
          uu.u[1] = hi ? p3 : o1;
          uu.u[2] = hi ? o2 : p0;
          uu.u[3] = hi ? o3 : p1;
          pa[2 * kh + c2] = uu.v;
        }
#pragma unroll
      for (int d0 = 0; d0 < 4; ++d0) {
        const int row = d0 * 32 + l31;
        const char* rb = bV + row * 128;
        const int swz = (row & 7) << 4;
#pragma unroll
        for (int ks = 0; ks < 4; ++ks) {
          const bf16x8 vb = *(const bf16x8*)(rb + ((((ks << 1) | hi) << 4) ^ swz));
          oacc[d0] = MFMA32(pa[ks], vb, oacc[d0]);
        }
      }
    }
    asm volatile("s_waitcnt vmcnt(0)" ::: "memory");
    __syncthreads();
  }

  if (!hi) lbuf[w][l31] = 1.0f / lsum;
  const int b = bh >> 4, h = bh & 15;
#pragma unroll
  for (int r = 0; r < 16; ++r) {
    const int cro = (r & 3) + 8 * (r >> 2) + 4 * hi;
    const float li = lbuf[w][cro];
    const size_t base = ((size_t)(b * S_LEN + qw + cro)) * DMODEL + h * DHEAD;
#pragma unroll
    for (int d0 = 0; d0 < 4; ++d0)
      ctx[base + d0 * 32 + l31] = (bf16_t)(oacc[d0][r] * li);
  }
}

// ------------------------------------------------------------------------- launch
extern "C" void kernel_launch(void* const* d_in, const int* in_sizes, int n_in,
                              void* d_out, int out_size, void* d_ws, size_t ws_size,
                              hipStream_t stream) {
  const float* x  = (const float*)d_in[0];
  const float* Wq = (const float*)d_in[1];
  const float* bq = (const float*)d_in[2];
  const float* Wk = (const float*)d_in[3];
  const float* bk = (const float*)d_in[4];
  const float* Wv = (const float*)d_in[5];
  const float* bv = (const float*)d_in[6];
  const float* Wo = (const float*)d_in[7];
  const float* bo = (const float*)d_in[8];

  char* ws = (char*)d_ws;
  const size_t MB = 1ull << 20;
  bf16_t* Xb  = (bf16_t*)(ws + 0);
  bf16_t* WqT = (bf16_t*)(ws + 16 * MB);
  bf16_t* WkT = (bf16_t*)(ws + 24 * MB);
  bf16_t* WvT = (bf16_t*)(ws + 32 * MB);
  bf16_t* WoT = (bf16_t*)(ws + 40 * MB);
  bf16_t* Qg  = (bf16_t*)(ws + 48 * MB);
  bf16_t* Kg  = (bf16_t*)(ws + 64 * MB);
  bf16_t* VTg = (bf16_t*)(ws + 80 * MB);   // V^T written directly by gemm_qkv
  bf16_t* Ctx = (bf16_t*)(ws + 96 * MB);
  if (ws_size < 112 * MB) return;

  prep_kernel<<<dim3(8192), 256, 0, stream>>>(x, Xb, Wq, Wk, Wv, Wo,
                                              WqT, WkT, WvT, WoT);
  gemm_qkv<<<dim3(768), 512, 0, stream>>>(
      Xb, WqT, WkT, WvT, bq, bk, bv, Qg, Kg, VTg);
  attn_kernel<<<dim3(512), 256, 0, stream>>>(Qg, Kg, VTg, Ctx);
  gemm_out<<<dim3(DMODEL / 256, MROWS / 128), 512, 0, stream>>>(Ctx, WoT, bo, (float*)d_out);
}